// Round 1
// 456.573 us; speedup vs baseline: 1.2882x; 1.2882x over previous
//
#include <hip/hip_runtime.h>

// ---------------------------------------------------------------------------
// SharedFusedMoE on MI355X (gfx950). fp32 inputs, FP32 outputs.
// T=4096, D=1024, I=512 (routed), E=16, top-2, SI=2048 (shared).
// Round 9: one-shot bf16 conversion of all operands + m97-class 128-tile
// GEMMs with global_load_lds(16B) staging (tiered on ws_size; old path kept
// as fallback so correctness is ws-independent).
// Output slot 0 = shared_out, slot 1 = fused_out (reference return order).
// ---------------------------------------------------------------------------

#define T_TOK 4096
#define NEXP  16

typedef __attribute__((ext_vector_type(8))) short   short8;   // 8 x bf16
typedef __attribute__((ext_vector_type(4))) float   floatx4;  // MFMA acc

typedef __attribute__((address_space(1))) void as1_void;
typedef __attribute__((address_space(3))) void as3_void;

__device__ __forceinline__ float bf2f(ushort u) {
    union { unsigned int i; float f; } v; v.i = ((unsigned int)u) << 16; return v.f;
}
__device__ __forceinline__ ushort f2bf(float f) {   // RNE, finite inputs
    unsigned int u = __builtin_bit_cast(unsigned int, f);
    unsigned int r = 0x7FFFu + ((u >> 16) & 1u);
    return (ushort)((u + r) >> 16);
}

__device__ __forceinline__ float load_elem(const void* p, long i, int bf) {
    return bf ? bf2f(((const ushort*)p)[i]) : ((const float*)p)[i];
}

// dtype probe (insurance): even ushort indices are real bf16 values
// (clustered exponent) if bf16 input, fp32 low-mantissa noise if fp32.
__global__ void detect_dtype(const ushort* __restrict__ xu, int* __restrict__ dflag) {
    __shared__ int cnt;
    if (threadIdx.x == 0) cnt = 0;
    __syncthreads();
    int ok = 0;
    for (int i = threadIdx.x; i < 512; i += 256) {
        int e = (xu[2 * i] >> 7) & 0xFF;
        ok += (e >= 90 && e <= 140) ? 1 : 0;
    }
    atomicAdd(&cnt, ok);
    __syncthreads();
    if (threadIdx.x == 0) *dflag = (cnt >= 384) ? 1 : 0;   // 1 = bf16, 0 = fp32
}

// scale probe (insurance): hidden_states std 1.0 vs w13_shared std 1/32.
__global__ void detect_xsel(const void* __restrict__ p0, const void* __restrict__ p4,
                            const int* __restrict__ dflag, int* __restrict__ xsel) {
    __shared__ float s0s, s4s;
    if (threadIdx.x == 0) { s0s = 0.f; s4s = 0.f; }
    __syncthreads();
    int bf = *dflag;
    float a0 = 0.f, a4 = 0.f;
    for (int i = threadIdx.x; i < 4096; i += 256) {
        a0 += fabsf(load_elem(p0, (long)i * 997 + 13, bf));
        a4 += fabsf(load_elem(p4, (long)i * 997 + 13, bf));
    }
    atomicAdd(&s0s, a0);
    atomicAdd(&s4s, a4);
    __syncthreads();
    if (threadIdx.x == 0) *xsel = (s0s >= s4s) ? 0 : 1;
}

// Router: softmax -> top-2 -> renormalize (denominators cancel).
__device__ __forceinline__ void top2(const void* logits, int t, int bf,
                                     int& b0, int& b1, float& w0, float& w1) {
    float l[16];
#pragma unroll
    for (int j = 0; j < 16; ++j) l[j] = load_elem(logits, t * 16 + j, bf);
    b0 = 0; float v0 = l[0];
#pragma unroll
    for (int j = 1; j < 16; ++j) { if (l[j] > v0) { v0 = l[j]; b0 = j; } }
    b1 = -1; float v1 = -3.4e38f;
#pragma unroll
    for (int j = 0; j < 16; ++j) {
        if (j == b0) continue;
        if (l[j] > v1) { v1 = l[j]; b1 = j; }
    }
    float d = __expf(v1 - v0);
    w0 = 1.0f / (1.0f + d);
    w1 = d / (1.0f + d);
}

__global__ void router_counts(const void* __restrict__ logits, const int* __restrict__ dflag,
                              int* __restrict__ counts) {
    int t = blockIdx.x * blockDim.x + threadIdx.x;
    if (t >= T_TOK) return;
    int b0, b1; float w0, w1;
    top2(logits, t, *dflag, b0, b1, w0, w1);
    atomicAdd(&counts[b0], 1);
    atomicAdd(&counts[b1], 1);
}

__global__ void scan_kernel(const int* __restrict__ counts, int* __restrict__ offsets) {
    if (threadIdx.x == 0 && blockIdx.x == 0) {
        int acc = 0;
        for (int e = 0; e < NEXP; ++e) { offsets[e] = acc; acc += counts[e]; }
    }
}

__global__ void router_pairs(const void* __restrict__ logits, const int* __restrict__ dflag,
                             const int* __restrict__ offsets, int* __restrict__ cursor,
                             int* __restrict__ pairinfo, float* __restrict__ pairw) {
    int t = blockIdx.x * blockDim.x + threadIdx.x;
    if (t >= T_TOK) return;
    int b0, b1; float w0, w1;
    top2(logits, t, *dflag, b0, b1, w0, w1);
    int p0 = offsets[b0] + atomicAdd(&cursor[b0], 1);
    pairinfo[p0] = 2 * t;     pairw[p0] = w0;
    int p1 = offsets[b1] + atomicAdd(&cursor[b1], 1);
    pairinfo[p1] = 2 * t + 1; pairw[p1] = w1;
}

// ---------------------------------------------------------------------------
// One-shot fp32 -> bf16 conversion (memory-bound, 16B stores). If pB != null
// and *xsel, source swaps to pB (hidden/w13_shared input-order hedge). If
// inputs are already bf16 (*dflag), straight 16B copy.
// ---------------------------------------------------------------------------
__global__ void to_bf16(const void* __restrict__ pA, const void* __restrict__ pB,
                        ushort* __restrict__ dst, long n8,
                        const int* __restrict__ dflag, const int* __restrict__ xsel)
{
    const void* src = (pB != nullptr && *xsel) ? pB : pA;
    const int bf = *dflag;
    long i = (long)blockIdx.x * blockDim.x + threadIdx.x;
    const long stride = (long)gridDim.x * blockDim.x;
    for (; i < n8; i += stride) {
        uint4 v;
        if (bf) {
            v = ((const uint4*)src)[i];
        } else {
            float4 f0 = ((const float4*)src)[i * 2];
            float4 f1 = ((const float4*)src)[i * 2 + 1];
            v.x = (unsigned)f2bf(f0.x) | ((unsigned)f2bf(f0.y) << 16);
            v.y = (unsigned)f2bf(f0.z) | ((unsigned)f2bf(f0.w) << 16);
            v.z = (unsigned)f2bf(f1.x) | ((unsigned)f2bf(f1.y) << 16);
            v.w = (unsigned)f2bf(f1.z) | ((unsigned)f2bf(f1.w) << 16);
        }
        ((uint4*)dst)[i] = v;
    }
}

// ---------------------------------------------------------------------------
// m97-class bf16 NT GEMM: 128-row tile, BK=64, 256 thr = 4 waves (2x2).
// Plain: BN=128, wave = 4x4 frags of 16x16x32. SWIGLU: BN=64 (gate+up tiles),
// wave = 4x2 + 4x2 frags. Staging = global_load_lds dwordx4: LDS dest is
// wave-uniform base + lane*16 (linear [rows][64] bf16 tile, no padding);
// global source is per-lane (supports the gather). Frag maps as in old
// kernel: A/B lane L elem j -> row (L&15), k=(L>>4)*8+j; C/D col=L&15,
// row=(L>>4)*4+reg.
// ---------------------------------------------------------------------------
__device__ __forceinline__ void gload16(const ushort* g, ushort* l) {
    __builtin_amdgcn_global_load_lds((as1_void*)g, (as3_void*)l, 16, 0, 0);
}

template <int SWIGLU, int GATHER, int ROUTED, int SCATTER>
__global__ __launch_bounds__(256)
void gemm_fast(const ushort* __restrict__ A, int lda,
               const ushort* __restrict__ B0, long upoff, long strideB, int ldb,
               void* __restrict__ C, int ldc, float* __restrict__ C2,
               int M, int K,
               const int* __restrict__ counts, const int* __restrict__ offsets,
               const int* __restrict__ pairinfo, const float* __restrict__ pairw)
{
    constexpr int BN  = SWIGLU ? 64 : 128;  // output cols per block (per matrix)
    constexpr int NBI = SWIGLU ? 2 : 4;     // B-stage instrs per wave per K-step
    constexpr int NFN = SWIGLU ? 2 : 4;     // 16-col frags per wave

    const int e    = ROUTED ? (int)blockIdx.z : 0;
    const int Mloc = ROUTED ? counts[e] : M;
    const int m0   = blockIdx.y * 128;
    if (m0 >= Mloc) return;
    const int n0   = blockIdx.x * BN;
    const int pair_base = ROUTED ? offsets[e] : 0;
    const long bbase    = ROUTED ? (long)e * strideB : 0L;

    __shared__ __align__(16) ushort As [128 * 64];
    __shared__ __align__(16) ushort Bs0[BN * 64];
    __shared__ __align__(16) ushort Bs1[SWIGLU ? BN * 64 : 8];

    const int tid  = threadIdx.x;
    const int lane = tid & 63;
    const int wave = tid >> 6;
    const int srow = lane >> 3;        // row within 8-row stage group
    const int scol = (lane & 7) * 8;   // bf16 col within 64-wide row

    // Per-thread global row bases (constant across K) for staging instrs.
    long aoff[4];
#pragma unroll
    for (int i = 0; i < 4; ++i) {
        int rl  = m0 + (wave * 4 + i) * 8 + srow;
        int rlc = rl < Mloc ? rl : Mloc - 1;
        long gr;
        if (GATHER)      gr = (long)(pairinfo[pair_base + rlc] >> 1);
        else if (ROUTED) gr = pair_base + rlc;
        else             gr = rlc;
        aoff[i] = gr * (long)lda + scol;
    }
    long boff[NBI];
#pragma unroll
    for (int i = 0; i < NBI; ++i) {
        int r = (wave * NBI + i) * 8 + srow;
        boff[i] = bbase + (long)(n0 + r) * ldb + scol;
    }

    const int wm   = (wave >> 1) * 64;
    const int wn   = (wave & 1) * (SWIGLU ? 32 : 64);
    const int r16  = lane & 15;
    const int quad = lane >> 4;

    const floatx4 z4 = {0.f, 0.f, 0.f, 0.f};
    floatx4 accg[4][NFN], accu[4][NFN];
#pragma unroll
    for (int mi = 0; mi < 4; ++mi)
#pragma unroll
        for (int ni = 0; ni < NFN; ++ni) { accg[mi][ni] = z4; accu[mi][ni] = z4; }

    for (int k0 = 0; k0 < K; k0 += 64) {
#pragma unroll
        for (int i = 0; i < 4; ++i)
            gload16(A + aoff[i] + k0, &As[(wave * 4 + i) * 512]);
#pragma unroll
        for (int i = 0; i < NBI; ++i) {
            gload16(B0 + boff[i] + k0, &Bs0[(wave * NBI + i) * 512]);
            if constexpr (SWIGLU)
                gload16(B0 + boff[i] + upoff + k0, &Bs1[(wave * NBI + i) * 512]);
        }
        __syncthreads();   // compiler drains vmcnt before s_barrier
#pragma unroll
        for (int kc = 0; kc < 2; ++kc) {
            const int kof = kc * 32 + quad * 8;
            short8 af[4];
#pragma unroll
            for (int mi = 0; mi < 4; ++mi)
                af[mi] = *(const short8*)&As[(wm + mi * 16 + r16) * 64 + kof];
            short8 bfr[NFN], ufr[NFN];
#pragma unroll
            for (int ni = 0; ni < NFN; ++ni) {
                bfr[ni] = *(const short8*)&Bs0[(wn + ni * 16 + r16) * 64 + kof];
                if constexpr (SWIGLU)
                    ufr[ni] = *(const short8*)&Bs1[(wn + ni * 16 + r16) * 64 + kof];
            }
#pragma unroll
            for (int mi = 0; mi < 4; ++mi)
#pragma unroll
                for (int ni = 0; ni < NFN; ++ni) {
                    accg[mi][ni] = __builtin_amdgcn_mfma_f32_16x16x32_bf16(
                        af[mi], bfr[ni], accg[mi][ni], 0, 0, 0);
                    if constexpr (SWIGLU)
                        accu[mi][ni] = __builtin_amdgcn_mfma_f32_16x16x32_bf16(
                            af[mi], ufr[ni], accu[mi][ni], 0, 0, 0);
                }
        }
        __syncthreads();
    }

#pragma unroll
    for (int mi = 0; mi < 4; ++mi) {
#pragma unroll
        for (int r = 0; r < 4; ++r) {
            const int grow = m0 + wm + mi * 16 + quad * 4 + r;
            if (grow >= Mloc) continue;
            int info = 0; float w = 0.f;
            if constexpr (SCATTER) {
                const int p = pair_base + grow;
                info = pairinfo[p]; w = pairw[p];
            }
#pragma unroll
            for (int ni = 0; ni < NFN; ++ni) {
                const int col = n0 + wn + ni * 16 + r16;
                float val;
                if constexpr (SWIGLU) {
                    float g = accg[mi][ni][r];
                    float u = accu[mi][ni][r];
                    val = (g / (1.0f + __expf(-g))) * u;   // silu(g)*u
                } else {
                    val = accg[mi][ni][r];
                }
                if constexpr (SCATTER) {
                    long idx = (long)(info >> 1) * 1024 + col;
                    float* dst = (info & 1) ? C2 : (float*)C;
                    dst[idx] = w * val;
                } else if constexpr (SWIGLU) {
                    long crow = ROUTED ? (long)(pair_base + grow) : (long)grow;
                    ((ushort*)C)[crow * ldc + col] = f2bf(val);   // bf16 act
                } else {
                    ((float*)C)[(long)grow * ldc + col] = val;    // fp32 out
                }
            }
        }
    }
}

// ---------------------------------------------------------------------------
// Fallback GEMM (previous session's kernel, verbatim) — used when ws_size is
// too small for the bf16 conversion buffers.
// ---------------------------------------------------------------------------
__device__ __forceinline__ void stage8(const void* __restrict__ src, long eoff, int bf,
                                       ushort* __restrict__ dst) {
    if (bf) {
        *(uint4*)dst = *(const uint4*)((const ushort*)src + eoff);
    } else {
        const float* s = (const float*)src + eoff;
        float4 f0 = *(const float4*)s;
        float4 f1 = *(const float4*)(s + 4);
        uint4 v;
        v.x = (unsigned)f2bf(f0.x) | ((unsigned)f2bf(f0.y) << 16);
        v.y = (unsigned)f2bf(f0.z) | ((unsigned)f2bf(f0.w) << 16);
        v.z = (unsigned)f2bf(f1.x) | ((unsigned)f2bf(f1.y) << 16);
        v.w = (unsigned)f2bf(f1.z) | ((unsigned)f2bf(f1.w) << 16);
        *(uint4*)dst = v;
    }
}

template <int SWIGLU, int GATHER, int ROUTED, int SCATTER, int LOCAL,
          int A_DT, int B_DT, int C_F32>
__global__ __launch_bounds__(256)
void gemm_nt(const void* __restrict__ A, const void* __restrict__ Aalt, int lda,
             const void* __restrict__ B0, const void* __restrict__ B0alt,
             long upoff, long strideB,
             void* __restrict__ C, int ldc, void* __restrict__ C2,
             int M, int K, int row0,
             const int* __restrict__ dflag, const int* __restrict__ xsel,
             const int* __restrict__ counts, const int* __restrict__ offsets,
             const int* __restrict__ pairinfo, const float* __restrict__ pairw,
             int e_base, int m_base, int Mcap)
{
    const int dfl = (A_DT && B_DT) ? 1 : *dflag;
    const int abf = A_DT ? 1 : dfl;
    const int bbf = B_DT ? 1 : dfl;
    if (Aalt  && *xsel) A  = Aalt;
    if (B0alt && *xsel) B0 = B0alt;

    const int e = ROUTED ? (e_base + (int)blockIdx.z) : 0;
    int Mloc;
    if (ROUTED) {
        int avail = counts[e] - m_base;
        Mloc = avail < Mcap ? avail : Mcap;
    } else {
        Mloc = M;
    }
    const int m0 = blockIdx.y * 64;
    if (m0 >= Mloc) return;
    const int n0 = blockIdx.x * 64;
    const int pair_base = ROUTED ? (offsets[e] + m_base) : 0;
    const int abase     = ROUTED ? (LOCAL ? 0 : offsets[e]) : 0;
    const long bbase    = ROUTED ? (long)e * strideB : 0L;

    constexpr int LS = 72;
    __shared__ __align__(16) ushort As[64 * LS];
    __shared__ __align__(16) ushort Bs0[64 * LS];
    __shared__ __align__(16) ushort Bs1[SWIGLU ? 64 * LS : 8];

    const int tid = threadIdx.x;

    int  lofs[2];
    long aoff[2], boff[2];
#pragma unroll
    for (int i = 0; i < 2; ++i) {
        int idx = tid + i * 256;
        int row = idx >> 3;
        int col = (idx & 7) * 8;
        lofs[i] = row * LS + col;
        int rl  = m0 + row;
        int rlc = rl < Mloc ? rl : (Mloc - 1);
        long rA;
        if (GATHER)      rA = (long)(pairinfo[pair_base + rlc] >> 1);
        else if (ROUTED) rA = abase + rlc;
        else             rA = row0 + rl;
        aoff[i] = rA * (long)lda + col;
        boff[i] = bbase + (long)(n0 + row) * K + col;
    }

    const int lane = tid & 63;
    const int wave = tid >> 6;
    const int wm   = (wave >> 1) * 32;
    const int wn   = (wave & 1) * 32;
    const int r16  = lane & 15;
    const int quad = lane >> 4;

    floatx4 accg[2][2] = {{{0.f,0.f,0.f,0.f},{0.f,0.f,0.f,0.f}},{{0.f,0.f,0.f,0.f},{0.f,0.f,0.f,0.f}}};
    floatx4 accu[2][2] = {{{0.f,0.f,0.f,0.f},{0.f,0.f,0.f,0.f}},{{0.f,0.f,0.f,0.f},{0.f,0.f,0.f,0.f}}};

    for (int k0 = 0; k0 < K; k0 += 64) {
#pragma unroll
        for (int i = 0; i < 2; ++i) {
            stage8(A,  aoff[i] + k0, abf, &As[lofs[i]]);
            stage8(B0, boff[i] + k0, bbf, &Bs0[lofs[i]]);
            if (SWIGLU) stage8(B0, boff[i] + k0 + upoff, bbf, &Bs1[lofs[i]]);
        }
        __syncthreads();
#pragma unroll
        for (int kc = 0; kc < 2; ++kc) {
            const int kof = kc * 32 + quad * 8;
            short8 a0 = *(const short8*)&As[(wm + r16)      * LS + kof];
            short8 a1 = *(const short8*)&As[(wm + 16 + r16) * LS + kof];
            short8 b0 = *(const short8*)&Bs0[(wn + r16)      * LS + kof];
            short8 b1 = *(const short8*)&Bs0[(wn + 16 + r16) * LS + kof];
            accg[0][0] = __builtin_amdgcn_mfma_f32_16x16x32_bf16(a0, b0, accg[0][0], 0, 0, 0);
            accg[0][1] = __builtin_amdgcn_mfma_f32_16x16x32_bf16(a0, b1, accg[0][1], 0, 0, 0);
            accg[1][0] = __builtin_amdgcn_mfma_f32_16x16x32_bf16(a1, b0, accg[1][0], 0, 0, 0);
            accg[1][1] = __builtin_amdgcn_mfma_f32_16x16x32_bf16(a1, b1, accg[1][1], 0, 0, 0);
            if (SWIGLU) {
                short8 u0 = *(const short8*)&Bs1[(wn + r16)      * LS + kof];
                short8 u1 = *(const short8*)&Bs1[(wn + 16 + r16) * LS + kof];
                accu[0][0] = __builtin_amdgcn_mfma_f32_16x16x32_bf16(a0, u0, accu[0][0], 0, 0, 0);
                accu[0][1] = __builtin_amdgcn_mfma_f32_16x16x32_bf16(a0, u1, accu[0][1], 0, 0, 0);
                accu[1][0] = __builtin_amdgcn_mfma_f32_16x16x32_bf16(a1, u0, accu[1][0], 0, 0, 0);
                accu[1][1] = __builtin_amdgcn_mfma_f32_16x16x32_bf16(a1, u1, accu[1][1], 0, 0, 0);
            }
        }
        __syncthreads();
    }

#pragma unroll
    for (int mi = 0; mi < 2; ++mi) {
#pragma unroll
        for (int ni = 0; ni < 2; ++ni) {
#pragma unroll
            for (int r = 0; r < 4; ++r) {
                int rowl = wm + mi * 16 + quad * 4 + r;
                int grow = m0 + rowl;
                if (grow < Mloc) {
                    int col = n0 + wn + ni * 16 + r16;
                    float g = accg[mi][ni][r];
                    float val;
                    if (SWIGLU) {
                        float u = accu[mi][ni][r];
                        val = (g / (1.0f + __expf(-g))) * u;
                    } else {
                        val = g;
                    }
                    if (SCATTER) {
                        int p    = pair_base + grow;
                        int info = pairinfo[p];
                        float w  = pairw[p];
                        long idx = (long)(info >> 1) * 1024 + col;
                        void* dst = (info & 1) ? C2 : C;
                        if (C_F32) ((float*)dst)[idx]  = w * val;
                        else       ((ushort*)dst)[idx] = f2bf(w * val);
                    } else {
                        int crow = ROUTED ? (abase + grow) : grow;
                        long idx = (long)crow * ldc + col;
                        if (C_F32) ((float*)C)[idx]  = val;
                        else       ((ushort*)C)[idx] = f2bf(val);
                    }
                }
            }
        }
    }
}

// outF[i] += outS[i]   (fp32, 4 elems/thread)
__global__ void add_kernel(float* __restrict__ outF, const float* __restrict__ outS, int n4) {
    int i = blockIdx.x * blockDim.x + threadIdx.x;
    if (i >= n4) return;
    float4 a = *(const float4*)(outF + (long)i * 4);
    float4 b = *(const float4*)(outS + (long)i * 4);
    a.x += b.x; a.y += b.y; a.z += b.z; a.w += b.w;
    *(float4*)(outF + (long)i * 4) = a;
}

// ---------------------------------------------------------------------------
extern "C" void kernel_launch(void* const* d_in, const int* in_sizes, int n_in,
                              void* d_out, int out_size, void* d_ws, size_t ws_size,
                              hipStream_t stream)
{
    const void* in0  = d_in[0];  // hidden_states [4096,1024] fp32
    const void* rl   = d_in[1];  // router_logits [4096,16]
    const void* w13  = d_in[2];  // [16,1024,1024]
    const void* w2   = d_in[3];  // [16,1024,512]
    const void* in4  = d_in[4];  // w13_shared [4096,1024]
    const void* w2s  = d_in[5];  // w2_shared [1024,2048]
    float* outS = (float*)d_out;                          // shared (final); temp rank1
    float* outF = (float*)d_out + (size_t)T_TOK * 1024;   // fused (final) + rank0

    // ---- metadata layout (66 KB) ----
    char*  base     = (char*)d_ws;
    int*   counts   = (int*)(base);
    int*   cursor   = (int*)(base + 64);
    int*   dflag    = (int*)(base + 128);
    int*   xsel     = (int*)(base + 132);
    int*   offsets  = (int*)(base + 192);
    int*   pairinfo = (int*)(base + 256);
    float* pairw    = (float*)(base + 256 + 32768);
    const size_t META = 256 + 65536;

    size_t avail = ws_size > META ? ws_size - META : 0;

    // ---- probes + routing (common) ----
    detect_dtype<<<1, 256, 0, stream>>>((const ushort*)in0, dflag);
    detect_xsel<<<1, 256, 0, stream>>>(in0, in4, dflag, xsel);
    hipMemsetAsync(counts, 0, 128, stream);    // counts + cursor
    router_counts<<<T_TOK / 256, 256, 0, stream>>>(rl, dflag, counts);
    scan_kernel<<<1, 64, 0, stream>>>(counts, offsets);
    router_pairs<<<T_TOK / 256, 256, 0, stream>>>(rl, dflag, offsets, cursor, pairinfo, pairw);

    const long sB1  = (long)1024 * 1024;   // w13 per-expert elements
    const long sB2  = (long)1024 * 512;    // w2 per-expert elements
    const long UP_R = (long)512 * 1024;    // routed up-offset within expert block
    const long UP_S = (long)2048 * 1024;   // shared up-offset in w13s

    const size_t FULL_NEED = 88080384ULL;  // hid+w13+w2+w13s+w2s bf16 + 16.8MB act
    const size_t MID_NEED  = 29360128ULL;  // act + hid + w13s + w2s bf16

    if (avail >= FULL_NEED) {
        // ================= FULL fast path: everything bf16 =================
        ushort* hidb  = (ushort*)(base + META);
        ushort* w13b  = hidb  + (size_t)4096 * 1024;
        ushort* w2b   = w13b  + (size_t)16 * 1024 * 1024;
        ushort* w13sb = w2b   + (size_t)16 * 1024 * 512;
        ushort* w2sb  = w13sb + (size_t)4096 * 1024;
        ushort* actb  = w2sb  + (size_t)1024 * 2048;   // 16.8MB: routed [8192,512] / shared [4096,2048]

        to_bf16<<<1024, 256, 0, stream>>>(in0, in4, hidb,  (long)4096 * 1024 / 8,      dflag, xsel);
        to_bf16<<<1024, 256, 0, stream>>>(w13, nullptr, w13b, (long)16 * 1024 * 1024 / 8, dflag, xsel);
        to_bf16<<<1024, 256, 0, stream>>>(w2,  nullptr, w2b,  (long)16 * 1024 * 512 / 8,  dflag, xsel);
        to_bf16<<<1024, 256, 0, stream>>>(in4, in0, w13sb, (long)4096 * 1024 / 8,      dflag, xsel);
        to_bf16<<<1024, 256, 0, stream>>>(w2s, nullptr, w2sb, (long)1024 * 2048 / 8,      dflag, xsel);

        // routed experts
        gemm_fast<1,1,1,0><<<dim3(8, 32, NEXP), 256, 0, stream>>>(
            hidb, 1024, w13b, UP_R, sB1, 1024, actb, 512, nullptr, 0, 1024,
            counts, offsets, pairinfo, pairw);
        gemm_fast<0,0,1,1><<<dim3(8, 32, NEXP), 256, 0, stream>>>(
            actb, 512, w2b, 0, sB2, 512, outF, 1024, outS, 0, 512,
            counts, offsets, pairinfo, pairw);
        add_kernel<<<(T_TOK * 1024 / 4 + 255) / 256, 256, 0, stream>>>(outF, outS, T_TOK * 1024 / 4);
        // shared expert (unchunked)
        gemm_fast<1,0,0,0><<<dim3(32, 32), 256, 0, stream>>>(
            hidb, 1024, w13sb, UP_S, 0, 1024, actb, 2048, nullptr, 4096, 1024,
            nullptr, nullptr, nullptr, nullptr);
        gemm_fast<0,0,0,0><<<dim3(8, 32), 256, 0, stream>>>(
            actb, 2048, w2sb, 0, 0, 2048, outS, 1024, nullptr, 4096, 2048,
            nullptr, nullptr, nullptr, nullptr);
    } else if (avail >= MID_NEED) {
        // ========== MID: fast shared path + improved old routed path =======
        ushort* act   = (ushort*)(base + META);              // 8.39MB (routed act / shared chunk)
        ushort* hidb  = act   + (size_t)8192 * 512;
        ushort* w13sb = hidb  + (size_t)4096 * 1024;
        ushort* w2sb  = w13sb + (size_t)4096 * 1024;

        to_bf16<<<1024, 256, 0, stream>>>(in0, in4, hidb,  (long)4096 * 1024 / 8, dflag, xsel);
        to_bf16<<<1024, 256, 0, stream>>>(in4, in0, w13sb, (long)4096 * 1024 / 8, dflag, xsel);
        to_bf16<<<1024, 256, 0, stream>>>(w2s, nullptr, w2sb, (long)1024 * 2048 / 8, dflag, xsel);

        // routed: old grouped kernels, A pre-converted to bf16
        gemm_nt<1,1,1,0,0,1,0,0><<<dim3(8, 64, NEXP), 256, 0, stream>>>(
            hidb, nullptr, 1024, w13, nullptr, UP_R, sB1, act, 512, nullptr, 0, 1024, 0,
            dflag, xsel, counts, offsets, pairinfo, pairw, 0, 0, T_TOK);
        gemm_nt<0,0,1,1,0,1,0,1><<<dim3(16, 64, NEXP), 256, 0, stream>>>(
            act, nullptr, 512, w2, nullptr, 0, sB2, outF, 1024, outS, 0, 512, 0,
            dflag, xsel, counts, offsets, pairinfo, pairw, 0, 0, T_TOK);
        add_kernel<<<(T_TOK * 1024 / 4 + 255) / 256, 256, 0, stream>>>(outF, outS, T_TOK * 1024 / 4);
        // shared: fast path, chunked CH=2048 (act reused)
        for (int c = 0; c < 2; ++c) {
            gemm_fast<1,0,0,0><<<dim3(32, 16), 256, 0, stream>>>(
                hidb + (size_t)c * 2048 * 1024, 1024, w13sb, UP_S, 0, 1024,
                act, 2048, nullptr, 2048, 1024, nullptr, nullptr, nullptr, nullptr);
            gemm_fast<0,0,0,0><<<dim3(8, 16), 256, 0, stream>>>(
                act, 2048, w2sb, 0, 0, 2048, outS + (size_t)c * 2048 * 1024, 1024, nullptr,
                2048, 2048, nullptr, nullptr, nullptr, nullptr);
        }
    } else {
        // ===================== fallback: previous kernel ===================
        const size_t MB = 1024 * 1024;
        int grouped, Mcap, CH;
        if      (avail >= 8 * MB) { grouped = 1; Mcap = T_TOK; CH = 2048; }
        else if (avail >= 1 * MB) { grouped = 0; Mcap = 1024;  CH = 256;  }
        else                      { grouped = 0; Mcap = 256;   CH = 64;   }
        ushort* act = (ushort*)(base + META);

        if (grouped) {
            gemm_nt<1,1,1,0,0,0,0,0><<<dim3(8, 64, NEXP), 256, 0, stream>>>(
                in0, in4, 1024, w13, nullptr, UP_R, sB1, act, 512, nullptr, 0, 1024, 0,
                dflag, xsel, counts, offsets, pairinfo, pairw, 0, 0, T_TOK);
            gemm_nt<0,0,1,1,0,1,0,1><<<dim3(16, 64, NEXP), 256, 0, stream>>>(
                act, nullptr, 512, w2, nullptr, 0, sB2, outF, 1024, outS, 0, 512, 0,
                dflag, xsel, counts, offsets, pairinfo, pairw, 0, 0, T_TOK);
        } else {
            for (int e = 0; e < NEXP; ++e) {
                for (int mb = 0; mb < T_TOK; mb += Mcap) {
                    gemm_nt<1,1,1,0,1,0,0,0><<<dim3(8, Mcap / 64, 1), 256, 0, stream>>>(
                        in0, in4, 1024, w13, nullptr, UP_R, sB1, act, 512, nullptr, 0, 1024, 0,
                        dflag, xsel, counts, offsets, pairinfo, pairw, e, mb, Mcap);
                    gemm_nt<0,0,1,1,1,1,0,1><<<dim3(16, Mcap / 64, 1), 256, 0, stream>>>(
                        act, nullptr, 512, w2, nullptr, 0, sB2, outF, 1024, outS, 0, 512, 0,
                        dflag, xsel, counts, offsets, pairinfo, pairw, e, mb, Mcap);
                }
            }
        }
        add_kernel<<<(T_TOK * 1024 / 4 + 255) / 256, 256, 0, stream>>>(outF, outS, T_TOK * 1024 / 4);
        for (int c = 0; c < T_TOK / CH; ++c) {
            gemm_nt<1,0,0,0,0,0,0,0><<<dim3(2048 / 64, CH / 64), 256, 0, stream>>>(
                in0, in4, 1024, in4, in0, UP_S, 0, act, 2048, nullptr, CH, 1024, c * CH,
                dflag, xsel, nullptr, nullptr, nullptr, nullptr, 0, 0, 0);
            gemm_nt<0,0,0,0,0,1,0,1><<<dim3(1024 / 64, CH / 64), 256, 0, stream>>>(
                act, nullptr, 2048, w2s, nullptr, 0, 0,
                outS + (size_t)c * CH * 1024, 1024, nullptr, CH, 2048, 0,
                dflag, xsel, nullptr, nullptr, nullptr, nullptr, 0, 0, 0);
        }
    }
    (void)in_sizes; (void)n_in; (void)out_size;
}

// Round 4
// 443.852 us; speedup vs baseline: 1.3251x; 1.0287x over previous
//
#include <hip/hip_runtime.h>

// ---------------------------------------------------------------------------
// SharedFusedMoE on MI355X (gfx950). fp32 inputs, FP32 outputs.
// T=4096, D=1024, I=512 (routed), E=16, top-2, SI=2048 (shared).
// Round 10 (2nd resubmit; rounds 2-3 were infra failures, no data):
// (a) T2 LDS XOR-swizzle via pre-swizzled global source (rule #21: linear
// global_load_lds dest + inverse-swizzled per-lane source + swizzled
// ds_read) kills the 16-way fragment-read bank conflict; (b) fuse independent
// GEMMs into two launches (g1 = routed-w13 + shared-w13, g2 = routed-w2 +
// shared-w2) to raise active blocks/CU from 2 to ~6; rank1 scatter goes to a
// workspace temp aliasing the dead hidb/w13sb region.
// Output slot 0 = shared_out, slot 1 = fused_out (reference return order).
// ---------------------------------------------------------------------------

#define T_TOK 4096
#define NEXP  16

typedef __attribute__((ext_vector_type(8))) short   short8;   // 8 x bf16
typedef __attribute__((ext_vector_type(4))) float   floatx4;  // MFMA acc

typedef __attribute__((address_space(1))) void as1_void;
typedef __attribute__((address_space(3))) void as3_void;

__device__ __forceinline__ float bf2f(ushort u) {
    union { unsigned int i; float f; } v; v.i = ((unsigned int)u) << 16; return v.f;
}
__device__ __forceinline__ ushort f2bf(float f) {   // RNE, finite inputs
    unsigned int u = __builtin_bit_cast(unsigned int, f);
    unsigned int r = 0x7FFFu + ((u >> 16) & 1u);
    return (ushort)((u + r) >> 16);
}

__device__ __forceinline__ float load_elem(const void* p, long i, int bf) {
    return bf ? bf2f(((const ushort*)p)[i]) : ((const float*)p)[i];
}

// dtype probe (insurance): even ushort indices are real bf16 values
// (clustered exponent) if bf16 input, fp32 low-mantissa noise if fp32.
__global__ void detect_dtype(const ushort* __restrict__ xu, int* __restrict__ dflag) {
    __shared__ int cnt;
    if (threadIdx.x == 0) cnt = 0;
    __syncthreads();
    int ok = 0;
    for (int i = threadIdx.x; i < 512; i += 256) {
        int e = (xu[2 * i] >> 7) & 0xFF;
        ok += (e >= 90 && e <= 140) ? 1 : 0;
    }
    atomicAdd(&cnt, ok);
    __syncthreads();
    if (threadIdx.x == 0) *dflag = (cnt >= 384) ? 1 : 0;   // 1 = bf16, 0 = fp32
}

// scale probe (insurance): hidden_states std 1.0 vs w13_shared std 1/32.
__global__ void detect_xsel(const void* __restrict__ p0, const void* __restrict__ p4,
                            const int* __restrict__ dflag, int* __restrict__ xsel) {
    __shared__ float s0s, s4s;
    if (threadIdx.x == 0) { s0s = 0.f; s4s = 0.f; }
    __syncthreads();
    int bf = *dflag;
    float a0 = 0.f, a4 = 0.f;
    for (int i = threadIdx.x; i < 4096; i += 256) {
        a0 += fabsf(load_elem(p0, (long)i * 997 + 13, bf));
        a4 += fabsf(load_elem(p4, (long)i * 997 + 13, bf));
    }
    atomicAdd(&s0s, a0);
    atomicAdd(&s4s, a4);
    __syncthreads();
    if (threadIdx.x == 0) *xsel = (s0s >= s4s) ? 0 : 1;
}

// Router: softmax -> top-2 -> renormalize (denominators cancel).
__device__ __forceinline__ void top2(const void* logits, int t, int bf,
                                     int& b0, int& b1, float& w0, float& w1) {
    float l[16];
#pragma unroll
    for (int j = 0; j < 16; ++j) l[j] = load_elem(logits, t * 16 + j, bf);
    b0 = 0; float v0 = l[0];
#pragma unroll
    for (int j = 1; j < 16; ++j) { if (l[j] > v0) { v0 = l[j]; b0 = j; } }
    b1 = -1; float v1 = -3.4e38f;
#pragma unroll
    for (int j = 0; j < 16; ++j) {
        if (j == b0) continue;
        if (l[j] > v1) { v1 = l[j]; b1 = j; }
    }
    float d = __expf(v1 - v0);
    w0 = 1.0f / (1.0f + d);
    w1 = d / (1.0f + d);
}

__global__ void router_counts(const void* __restrict__ logits, const int* __restrict__ dflag,
                              int* __restrict__ counts) {
    int t = blockIdx.x * blockDim.x + threadIdx.x;
    if (t >= T_TOK) return;
    int b0, b1; float w0, w1;
    top2(logits, t, *dflag, b0, b1, w0, w1);
    atomicAdd(&counts[b0], 1);
    atomicAdd(&counts[b1], 1);
}

__global__ void scan_kernel(const int* __restrict__ counts, int* __restrict__ offsets) {
    if (threadIdx.x == 0 && blockIdx.x == 0) {
        int acc = 0;
        for (int e = 0; e < NEXP; ++e) { offsets[e] = acc; acc += counts[e]; }
    }
}

__global__ void router_pairs(const void* __restrict__ logits, const int* __restrict__ dflag,
                             const int* __restrict__ offsets, int* __restrict__ cursor,
                             int* __restrict__ pairinfo, float* __restrict__ pairw) {
    int t = blockIdx.x * blockDim.x + threadIdx.x;
    if (t >= T_TOK) return;
    int b0, b1; float w0, w1;
    top2(logits, t, *dflag, b0, b1, w0, w1);
    int p0 = offsets[b0] + atomicAdd(&cursor[b0], 1);
    pairinfo[p0] = 2 * t;     pairw[p0] = w0;
    int p1 = offsets[b1] + atomicAdd(&cursor[b1], 1);
    pairinfo[p1] = 2 * t + 1; pairw[p1] = w1;
}

// ---------------------------------------------------------------------------
// One-shot fp32 -> bf16 conversion (memory-bound, 16B stores).
// ---------------------------------------------------------------------------
__global__ void to_bf16(const void* __restrict__ pA, const void* __restrict__ pB,
                        ushort* __restrict__ dst, long n8,
                        const int* __restrict__ dflag, const int* __restrict__ xsel)
{
    const void* src = (pB != nullptr && *xsel) ? pB : pA;
    const int bf = *dflag;
    long i = (long)blockIdx.x * blockDim.x + threadIdx.x;
    const long stride = (long)gridDim.x * blockDim.x;
    for (; i < n8; i += stride) {
        uint4 v;
        if (bf) {
            v = ((const uint4*)src)[i];
        } else {
            float4 f0 = ((const float4*)src)[i * 2];
            float4 f1 = ((const float4*)src)[i * 2 + 1];
            v.x = (unsigned)f2bf(f0.x) | ((unsigned)f2bf(f0.y) << 16);
            v.y = (unsigned)f2bf(f0.z) | ((unsigned)f2bf(f0.w) << 16);
            v.z = (unsigned)f2bf(f1.x) | ((unsigned)f2bf(f1.y) << 16);
            v.w = (unsigned)f2bf(f1.z) | ((unsigned)f2bf(f1.w) << 16);
        }
        ((uint4*)dst)[i] = v;
    }
}

// ---------------------------------------------------------------------------
// m97-class bf16 NT GEMM core. 128-row tile, BK=64, 256 thr = 4 waves (2x2).
// Plain: BN=128, wave = 4x4 frags of 16x16x32. SWIGLU: BN=64 (gate+up tiles),
// wave = 4x2 + 4x2 frags.
// T2 swizzle (rule #21): global_load_lds writes linearly (lane*16B); the
// per-lane GLOBAL source column group is c8 = (lane&7) ^ (lane>>3), so LDS
// physical 16B-slot s of row R holds logical col-group s ^ (R&7). Fragment
// reads use slot ((kc*4+quad) ^ (r16&7)) -> each 8-lane phase covers 8
// distinct slots (all 32 banks) -> conflict-free. Involution both sides.
// Frag maps: A/B lane L elem j -> row (L&15), k=(L>>4)*8+j; C/D col=L&15,
// row=(L>>4)*4+reg.
// ---------------------------------------------------------------------------
__device__ __forceinline__ void gload16(const ushort* g, ushort* l) {
    __builtin_amdgcn_global_load_lds((as1_void*)g, (as3_void*)l, 16, 0, 0);
}

template <int SWIGLU, int GATHER, int ROUTED, int SCATTER>
__device__ __forceinline__ void gemm_core(
    ushort* __restrict__ smem,
    const ushort* __restrict__ A, int lda,
    const ushort* __restrict__ B0, long upoff, long bbase, int ldb,
    void* __restrict__ C, int ldc, float* __restrict__ C2,
    int m0, int n0, int Mloc, int K, int pair_base,
    const int* __restrict__ pairinfo, const float* __restrict__ pairw)
{
    constexpr int NBI = SWIGLU ? 2 : 4;     // B-stage instrs per wave per K-step
    constexpr int NFN = SWIGLU ? 2 : 4;     // 16-col frags per wave

    ushort* As  = smem;                       // 128 x 64
    ushort* Bs0 = smem + 128 * 64;            // BN x 64
    ushort* Bs1 = SWIGLU ? (smem + 128 * 64 + 64 * 64) : nullptr;

    const int tid  = threadIdx.x;
    const int lane = tid & 63;
    const int wave = tid >> 6;
    const int srow = lane >> 3;                      // row within 8-row group
    const int scol = ((lane & 7) ^ srow) * 8;        // swizzled source col grp

    long aoff[4];
#pragma unroll
    for (int i = 0; i < 4; ++i) {
        int rl  = m0 + (wave * 4 + i) * 8 + srow;
        int rlc = rl < Mloc ? rl : Mloc - 1;
        long gr;
        if (GATHER)      gr = (long)(pairinfo[pair_base + rlc] >> 1);
        else if (ROUTED) gr = pair_base + rlc;
        else             gr = rlc;
        aoff[i] = gr * (long)lda + scol;
    }
    long boff[NBI];
#pragma unroll
    for (int i = 0; i < NBI; ++i) {
        int r = (wave * NBI + i) * 8 + srow;
        boff[i] = bbase + (long)(n0 + r) * ldb + scol;
    }

    const int wm   = (wave >> 1) * 64;
    const int wn   = (wave & 1) * (SWIGLU ? 32 : 64);
    const int r16  = lane & 15;
    const int quad = lane >> 4;
    const int rlow = r16 & 7;

    const floatx4 z4 = {0.f, 0.f, 0.f, 0.f};
    floatx4 accg[4][NFN], accu[4][NFN];
#pragma unroll
    for (int mi = 0; mi < 4; ++mi)
#pragma unroll
        for (int ni = 0; ni < NFN; ++ni) { accg[mi][ni] = z4; accu[mi][ni] = z4; }

    for (int k0 = 0; k0 < K; k0 += 64) {
#pragma unroll
        for (int i = 0; i < 4; ++i)
            gload16(A + aoff[i] + k0, &As[(wave * 4 + i) * 512]);
#pragma unroll
        for (int i = 0; i < NBI; ++i) {
            gload16(B0 + boff[i] + k0, &Bs0[(wave * NBI + i) * 512]);
            if constexpr (SWIGLU)
                gload16(B0 + boff[i] + upoff + k0, &Bs1[(wave * NBI + i) * 512]);
        }
        __syncthreads();   // compiler drains vmcnt before s_barrier
#pragma unroll
        for (int kc = 0; kc < 2; ++kc) {
            const int sw = ((kc * 4 + quad) ^ rlow) * 8;   // swizzled 16B slot
            short8 af[4];
#pragma unroll
            for (int mi = 0; mi < 4; ++mi)
                af[mi] = *(const short8*)&As[(wm + mi * 16 + r16) * 64 + sw];
            short8 bfr[NFN], ufr[NFN];
#pragma unroll
            for (int ni = 0; ni < NFN; ++ni) {
                bfr[ni] = *(const short8*)&Bs0[(wn + ni * 16 + r16) * 64 + sw];
                if constexpr (SWIGLU)
                    ufr[ni] = *(const short8*)&Bs1[(wn + ni * 16 + r16) * 64 + sw];
            }
#pragma unroll
            for (int mi = 0; mi < 4; ++mi)
#pragma unroll
                for (int ni = 0; ni < NFN; ++ni) {
                    accg[mi][ni] = __builtin_amdgcn_mfma_f32_16x16x32_bf16(
                        af[mi], bfr[ni], accg[mi][ni], 0, 0, 0);
                    if constexpr (SWIGLU)
                        accu[mi][ni] = __builtin_amdgcn_mfma_f32_16x16x32_bf16(
                            af[mi], ufr[ni], accu[mi][ni], 0, 0, 0);
                }
        }
        __syncthreads();
    }

#pragma unroll
    for (int mi = 0; mi < 4; ++mi) {
#pragma unroll
        for (int r = 0; r < 4; ++r) {
            const int grow = m0 + wm + mi * 16 + quad * 4 + r;
            if (grow >= Mloc) continue;
            int info = 0; float w = 0.f;
            if constexpr (SCATTER) {
                const int p = pair_base + grow;
                info = pairinfo[p]; w = pairw[p];
            }
#pragma unroll
            for (int ni = 0; ni < NFN; ++ni) {
                const int col = n0 + wn + ni * 16 + r16;
                float val;
                if constexpr (SWIGLU) {
                    float g = accg[mi][ni][r];
                    float u = accu[mi][ni][r];
                    val = (g / (1.0f + __expf(-g))) * u;   // silu(g)*u
                } else {
                    val = accg[mi][ni][r];
                }
                if constexpr (SCATTER) {
                    long idx = (long)(info >> 1) * 1024 + col;
                    float* dst = (info & 1) ? C2 : (float*)C;
                    dst[idx] = w * val;
                } else if constexpr (SWIGLU) {
                    long crow = ROUTED ? (long)(pair_base + grow) : (long)grow;
                    ((ushort*)C)[crow * ldc + col] = f2bf(val);   // bf16 act
                } else {
                    ((float*)C)[(long)grow * ldc + col] = val;    // fp32 out
                }
            }
        }
    }
}

// Thin wrapper (MID tier + non-fused FULL fallback keep this entry point).
template <int SWIGLU, int GATHER, int ROUTED, int SCATTER>
__global__ __launch_bounds__(256)
void gemm_fast(const ushort* __restrict__ A, int lda,
               const ushort* __restrict__ B0, long upoff, long strideB, int ldb,
               void* __restrict__ C, int ldc, float* __restrict__ C2,
               int M, int K,
               const int* __restrict__ counts, const int* __restrict__ offsets,
               const int* __restrict__ pairinfo, const float* __restrict__ pairw)
{
    __shared__ __align__(16) ushort smem[16384];
    const int e    = ROUTED ? (int)blockIdx.z : 0;
    const int Mloc = ROUTED ? counts[e] : M;
    const int m0   = blockIdx.y * 128;
    if (m0 >= Mloc) return;
    constexpr int BN = SWIGLU ? 64 : 128;
    const int n0  = blockIdx.x * BN;
    const int pb  = ROUTED ? offsets[e] : 0;
    const long bb = ROUTED ? (long)e * strideB : 0L;
    gemm_core<SWIGLU, GATHER, ROUTED, SCATTER>(
        smem, A, lda, B0, upoff, bb, ldb, C, ldc, C2,
        m0, n0, Mloc, K, pb, pairinfo, pairw);
}

// Fused L1: routed w13-SwiGLU (z<4, 4 experts per z-slice) + shared w13-SwiGLU
// (z==4). Grid (32, 32, 5).
__global__ __launch_bounds__(256)
void g1_fused(const ushort* __restrict__ hidb, const ushort* __restrict__ w13b,
              const ushort* __restrict__ w13sb,
              ushort* __restrict__ actR, ushort* __restrict__ actS,
              const int* __restrict__ counts, const int* __restrict__ offsets,
              const int* __restrict__ pairinfo)
{
    __shared__ __align__(16) ushort smem[16384];
    const int z  = blockIdx.z;
    const int m0 = blockIdx.y * 128;
    if (z < 4) {
        const int e    = z * 4 + ((int)blockIdx.x >> 3);
        const int Mloc = counts[e];
        if (m0 >= Mloc) return;
        const int n0 = ((int)blockIdx.x & 7) * 64;
        gemm_core<1, 1, 1, 0>(smem, hidb, 1024,
                              w13b, (long)512 * 1024, (long)e * 1024 * 1024, 1024,
                              actR, 512, nullptr,
                              m0, n0, Mloc, 1024, offsets[e], pairinfo, nullptr);
    } else {
        const int n0 = (int)blockIdx.x * 64;
        gemm_core<1, 0, 0, 0>(smem, hidb, 1024,
                              w13sb, (long)2048 * 1024, 0L, 1024,
                              actS, 2048, nullptr,
                              m0, n0, T_TOK, 1024, 0, nullptr, nullptr);
    }
}

// Fused L2: routed w2 + scatter (rank0->outF, rank1->outT) (z<4) + shared w2
// -> outS (z==4). Grid (32, 32, 5).
__global__ __launch_bounds__(256)
void g2_fused(const ushort* __restrict__ actR, const ushort* __restrict__ actS,
              const ushort* __restrict__ w2b, const ushort* __restrict__ w2sb,
              float* __restrict__ outF, float* __restrict__ outT,
              float* __restrict__ outS,
              const int* __restrict__ counts, const int* __restrict__ offsets,
              const int* __restrict__ pairinfo, const float* __restrict__ pairw)
{
    __shared__ __align__(16) ushort smem[16384];
    const int z  = blockIdx.z;
    const int m0 = blockIdx.y * 128;
    if (z < 4) {
        const int e    = z * 4 + ((int)blockIdx.x >> 3);
        const int Mloc = counts[e];
        if (m0 >= Mloc) return;
        const int n0 = ((int)blockIdx.x & 7) * 128;
        gemm_core<0, 0, 1, 1>(smem, actR, 512,
                              w2b, 0L, (long)e * 1024 * 512, 512,
                              outF, 1024, outT,
                              m0, n0, Mloc, 512, offsets[e], pairinfo, pairw);
    } else {
        if ((int)blockIdx.x >= 8) return;
        const int n0 = (int)blockIdx.x * 128;
        gemm_core<0, 0, 0, 0>(smem, actS, 2048,
                              w2sb, 0L, 0L, 2048,
                              outS, 1024, nullptr,
                              m0, n0, T_TOK, 2048, 0, nullptr, nullptr);
    }
}

// ---------------------------------------------------------------------------
// Fallback GEMM (original session kernel, verbatim) — tiny-ws insurance.
// ---------------------------------------------------------------------------
__device__ __forceinline__ void stage8(const void* __restrict__ src, long eoff, int bf,
                                       ushort* __restrict__ dst) {
    if (bf) {
        *(uint4*)dst = *(const uint4*)((const ushort*)src + eoff);
    } else {
        const float* s = (const float*)src + eoff;
        float4 f0 = *(const float4*)s;
        float4 f1 = *(const float4*)(s + 4);
        uint4 v;
        v.x = (unsigned)f2bf(f0.x) | ((unsigned)f2bf(f0.y) << 16);
        v.y = (unsigned)f2bf(f0.z) | ((unsigned)f2bf(f0.w) << 16);
        v.z = (unsigned)f2bf(f1.x) | ((unsigned)f2bf(f1.y) << 16);
        v.w = (unsigned)f2bf(f1.z) | ((unsigned)f2bf(f1.w) << 16);
        *(uint4*)dst = v;
    }
}

template <int SWIGLU, int GATHER, int ROUTED, int SCATTER, int LOCAL,
          int A_DT, int B_DT, int C_F32>
__global__ __launch_bounds__(256)
void gemm_nt(const void* __restrict__ A, const void* __restrict__ Aalt, int lda,
             const void* __restrict__ B0, const void* __restrict__ B0alt,
             long upoff, long strideB,
             void* __restrict__ C, int ldc, void* __restrict__ C2,
             int M, int K, int row0,
             const int* __restrict__ dflag, const int* __restrict__ xsel,
             const int* __restrict__ counts, const int* __restrict__ offsets,
             const int* __restrict__ pairinfo, const float* __restrict__ pairw,
             int e_base, int m_base, int Mcap)
{
    const int dfl = (A_DT && B_DT) ? 1 : *dflag;
    const int abf = A_DT ? 1 : dfl;
    const int bbf = B_DT ? 1 : dfl;
    if (Aalt  && *xsel) A  = Aalt;
    if (B0alt && *xsel) B0 = B0alt;

    const int e = ROUTED ? (e_base + (int)blockIdx.z) : 0;
    int Mloc;
    if (ROUTED) {
        int avail = counts[e] - m_base;
        Mloc = avail < Mcap ? avail : Mcap;
    } else {
        Mloc = M;
    }
    const int m0 = blockIdx.y * 64;
    if (m0 >= Mloc) return;
    const int n0 = blockIdx.x * 64;
    const int pair_base = ROUTED ? (offsets[e] + m_base) : 0;
    const int abase     = ROUTED ? (LOCAL ? 0 : offsets[e]) : 0;
    const long bbase    = ROUTED ? (long)e * strideB : 0L;

    constexpr int LS = 72;
    __shared__ __align__(16) ushort As[64 * LS];
    __shared__ __align__(16) ushort Bs0[64 * LS];
    __shared__ __align__(16) ushort Bs1[SWIGLU ? 64 * LS : 8];

    const int tid = threadIdx.x;

    int  lofs[2];
    long aoff[2], boff[2];
#pragma unroll
    for (int i = 0; i < 2; ++i) {
        int idx = tid + i * 256;
        int row = idx >> 3;
        int col = (idx & 7) * 8;
        lofs[i] = row * LS + col;
        int rl  = m0 + row;
        int rlc = rl < Mloc ? rl : (Mloc - 1);
        long rA;
        if (GATHER)      rA = (long)(pairinfo[pair_base + rlc] >> 1);
        else if (ROUTED) rA = abase + rlc;
        else             rA = row0 + rl;
        aoff[i] = rA * (long)lda + col;
        boff[i] = bbase + (long)(n0 + row) * K + col;
    }

    const int lane = tid & 63;
    const int wave = tid >> 6;
    const int wm   = (wave >> 1) * 32;
    const int wn   = (wave & 1) * 32;
    const int r16  = lane & 15;
    const int quad = lane >> 4;

    floatx4 accg[2][2] = {{{0.f,0.f,0.f,0.f},{0.f,0.f,0.f,0.f}},{{0.f,0.f,0.f,0.f},{0.f,0.f,0.f,0.f}}};
    floatx4 accu[2][2] = {{{0.f,0.f,0.f,0.f},{0.f,0.f,0.f,0.f}},{{0.f,0.f,0.f,0.f},{0.f,0.f,0.f,0.f}}};

    for (int k0 = 0; k0 < K; k0 += 64) {
#pragma unroll
        for (int i = 0; i < 2; ++i) {
            stage8(A,  aoff[i] + k0, abf, &As[lofs[i]]);
            stage8(B0, boff[i] + k0, bbf, &Bs0[lofs[i]]);
            if (SWIGLU) stage8(B0, boff[i] + k0 + upoff, bbf, &Bs1[lofs[i]]);
        }
        __syncthreads();
#pragma unroll
        for (int kc = 0; kc < 2; ++kc) {
            const int kof = kc * 32 + quad * 8;
            short8 a0 = *(const short8*)&As[(wm + r16)      * LS + kof];
            short8 a1 = *(const short8*)&As[(wm + 16 + r16) * LS + kof];
            short8 b0 = *(const short8*)&Bs0[(wn + r16)      * LS + kof];
            short8 b1 = *(const short8*)&Bs0[(wn + 16 + r16) * LS + kof];
            accg[0][0] = __builtin_amdgcn_mfma_f32_16x16x32_bf16(a0, b0, accg[0][0], 0, 0, 0);
            accg[0][1] = __builtin_amdgcn_mfma_f32_16x16x32_bf16(a0, b1, accg[0][1], 0, 0, 0);
            accg[1][0] = __builtin_amdgcn_mfma_f32_16x16x32_bf16(a1, b0, accg[1][0], 0, 0, 0);
            accg[1][1] = __builtin_amdgcn_mfma_f32_16x16x32_bf16(a1, b1, accg[1][1], 0, 0, 0);
            if (SWIGLU) {
                short8 u0 = *(const short8*)&Bs1[(wn + r16)      * LS + kof];
                short8 u1 = *(const short8*)&Bs1[(wn + 16 + r16) * LS + kof];
                accu[0][0] = __builtin_amdgcn_mfma_f32_16x16x32_bf16(a0, u0, accu[0][0], 0, 0, 0);
                accu[0][1] = __builtin_amdgcn_mfma_f32_16x16x32_bf16(a0, u1, accu[0][1], 0, 0, 0);
                accu[1][0] = __builtin_amdgcn_mfma_f32_16x16x32_bf16(a1, u0, accu[1][0], 0, 0, 0);
                accu[1][1] = __builtin_amdgcn_mfma_f32_16x16x32_bf16(a1, u1, accu[1][1], 0, 0, 0);
            }
        }
        __syncthreads();
    }

#pragma unroll
    for (int mi = 0; mi < 2; ++mi) {
#pragma unroll
        for (int ni = 0; ni < 2; ++ni) {
#pragma unroll
            for (int r = 0; r < 4; ++r) {
                int rowl = wm + mi * 16 + quad * 4 + r;
                int grow = m0 + rowl;
                if (grow < Mloc) {
                    int col = n0 + wn + ni * 16 + r16;
                    float g = accg[mi][ni][r];
                    float val;
                    if (SWIGLU) {
                        float u = accu[mi][ni][r];
                        val = (g / (1.0f + __expf(-g))) * u;
                    } else {
                        val = g;
                    }
                    if (SCATTER) {
                        int p    = pair_base + grow;
                        int info = pairinfo[p];
                        float w  = pairw[p];
                        long idx = (long)(info >> 1) * 1024 + col;
                        void* dst = (info & 1) ? C2 : C;
                        if (C_F32) ((float*)dst)[idx]  = w * val;
                        else       ((ushort*)dst)[idx] = f2bf(w * val);
                    } else {
                        int crow = ROUTED ? (abase + grow) : grow;
                        long idx = (long)crow * ldc + col;
                        if (C_F32) ((float*)C)[idx]  = val;
                        else       ((ushort*)C)[idx] = f2bf(val);
                    }
                }
            }
        }
    }
}

// outF[i] += outT[i]   (fp32, 4 elems/thread)
__global__ void add_kernel(float* __restrict__ outF, const float* __restrict__ outT, int n4) {
    int i = blockIdx.x * blockDim.x + threadIdx.x;
    if (i >= n4) return;
    float4 a = *(const float4*)(outF + (long)i * 4);
    float4 b = *(const float4*)(outT + (long)i * 4);
    a.x += b.x; a.y += b.y; a.z += b.z; a.w += b.w;
    *(float4*)(outF + (long)i * 4) = a;
}

// ---------------------------------------------------------------------------
extern "C" void kernel_launch(void* const* d_in, const int* in_sizes, int n_in,
                              void* d_out, int out_size, void* d_ws, size_t ws_size,
                              hipStream_t stream)
{
    const void* in0  = d_in[0];  // hidden_states [4096,1024] fp32
    const void* rl   = d_in[1];  // router_logits [4096,16]
    const void* w13  = d_in[2];  // [16,1024,1024]
    const void* w2   = d_in[3];  // [16,1024,512]
    const void* in4  = d_in[4];  // w13_shared [4096,1024]
    const void* w2s  = d_in[5];  // w2_shared [1024,2048]
    float* outS = (float*)d_out;                          // shared (final)
    float* outF = (float*)d_out + (size_t)T_TOK * 1024;   // fused (final)

    // ---- metadata layout (66 KB) ----
    char*  base     = (char*)d_ws;
    int*   counts   = (int*)(base);
    int*   cursor   = (int*)(base + 64);
    int*   dflag    = (int*)(base + 128);
    int*   xsel     = (int*)(base + 132);
    int*   offsets  = (int*)(base + 192);
    int*   pairinfo = (int*)(base + 256);
    float* pairw    = (float*)(base + 256 + 32768);
    const size_t META = 256 + 65536;

    size_t avail = ws_size > META ? ws_size - META : 0;

    // ---- probes + routing (common) ----
    detect_dtype<<<1, 256, 0, stream>>>((const ushort*)in0, dflag);
    detect_xsel<<<1, 256, 0, stream>>>(in0, in4, dflag, xsel);
    hipMemsetAsync(counts, 0, 128, stream);    // counts + cursor
    router_counts<<<T_TOK / 256, 256, 0, stream>>>(rl, dflag, counts);
    scan_kernel<<<1, 64, 0, stream>>>(counts, offsets);
    router_pairs<<<T_TOK / 256, 256, 0, stream>>>(rl, dflag, offsets, cursor, pairinfo, pairw);

    const long sB1  = (long)1024 * 1024;   // w13 per-expert elements
    const long sB2  = (long)1024 * 512;    // w2 per-expert elements
    const long UP_R = (long)512 * 1024;    // routed up-offset within expert block
    const long UP_S = (long)2048 * 1024;   // shared up-offset in w13s

    const size_t FULL2_NEED = 96468992ULL;  // all-bf16 + actR + actS (outT aliases hidb+w13sb)
    const size_t FULL_NEED  = 88080384ULL;  // all-bf16 + single shared act
    const size_t MID_NEED   = 29360128ULL;  // act + hid + w13s + w2s bf16

    if (avail >= FULL2_NEED) {
        // ============ FULL2: bf16 everywhere + fused launches =============
        ushort* hidb  = (ushort*)(base + META);
        ushort* w13sb = hidb  + (size_t)4096 * 1024;
        ushort* w13b  = w13sb + (size_t)4096 * 1024;
        ushort* w2b   = w13b  + (size_t)16 * 1024 * 1024;
        ushort* w2sb  = w2b   + (size_t)16 * 1024 * 512;
        ushort* actR  = w2sb  + (size_t)1024 * 2048;     // [8192, 512] bf16
        ushort* actS  = actR  + (size_t)8192 * 512;      // [4096, 2048] bf16
        float*  outT  = (float*)hidb;   // rank1 temp; aliases hidb+w13sb (dead after g1)

        to_bf16<<<1024, 256, 0, stream>>>(in0, in4, hidb,  (long)4096 * 1024 / 8,      dflag, xsel);
        to_bf16<<<1024, 256, 0, stream>>>(in4, in0, w13sb, (long)4096 * 1024 / 8,      dflag, xsel);
        to_bf16<<<1024, 256, 0, stream>>>(w13, nullptr, w13b, (long)16 * 1024 * 1024 / 8, dflag, xsel);
        to_bf16<<<1024, 256, 0, stream>>>(w2,  nullptr, w2b,  (long)16 * 1024 * 512 / 8,  dflag, xsel);
        to_bf16<<<1024, 256, 0, stream>>>(w2s, nullptr, w2sb, (long)1024 * 2048 / 8,      dflag, xsel);

        g1_fused<<<dim3(32, 32, 5), 256, 0, stream>>>(
            hidb, w13b, w13sb, actR, actS, counts, offsets, pairinfo);
        g2_fused<<<dim3(32, 32, 5), 256, 0, stream>>>(
            actR, actS, w2b, w2sb, outF, outT, outS,
            counts, offsets, pairinfo, pairw);
        add_kernel<<<(T_TOK * 1024 / 4 + 255) / 256, 256, 0, stream>>>(outF, outT, T_TOK * 1024 / 4);
    } else if (avail >= FULL_NEED) {
        // ====== FULL: bf16 everywhere, sequential launches (round-1) ======
        ushort* hidb  = (ushort*)(base + META);
        ushort* w13b  = hidb  + (size_t)4096 * 1024;
        ushort* w2b   = w13b  + (size_t)16 * 1024 * 1024;
        ushort* w13sb = w2b   + (size_t)16 * 1024 * 512;
        ushort* w2sb  = w13sb + (size_t)4096 * 1024;
        ushort* actb  = w2sb  + (size_t)1024 * 2048;

        to_bf16<<<1024, 256, 0, stream>>>(in0, in4, hidb,  (long)4096 * 1024 / 8,      dflag, xsel);
        to_bf16<<<1024, 256, 0, stream>>>(w13, nullptr, w13b, (long)16 * 1024 * 1024 / 8, dflag, xsel);
        to_bf16<<<1024, 256, 0, stream>>>(w2,  nullptr, w2b,  (long)16 * 1024 * 512 / 8,  dflag, xsel);
        to_bf16<<<1024, 256, 0, stream>>>(in4, in0, w13sb, (long)4096 * 1024 / 8,      dflag, xsel);
        to_bf16<<<1024, 256, 0, stream>>>(w2s, nullptr, w2sb, (long)1024 * 2048 / 8,      dflag, xsel);

        gemm_fast<1,1,1,0><<<dim3(8, 32, NEXP), 256, 0, stream>>>(
            hidb, 1024, w13b, UP_R, sB1, 1024, actb, 512, nullptr, 0, 1024,
            counts, offsets, pairinfo, pairw);
        gemm_fast<0,0,1,1><<<dim3(8, 32, NEXP), 256, 0, stream>>>(
            actb, 512, w2b, 0, sB2, 512, outF, 1024, outS, 0, 512,
            counts, offsets, pairinfo, pairw);
        add_kernel<<<(T_TOK * 1024 / 4 + 255) / 256, 256, 0, stream>>>(outF, outS, T_TOK * 1024 / 4);
        gemm_fast<1,0,0,0><<<dim3(32, 32), 256, 0, stream>>>(
            hidb, 1024, w13sb, UP_S, 0, 1024, actb, 2048, nullptr, 4096, 1024,
            nullptr, nullptr, nullptr, nullptr);
        gemm_fast<0,0,0,0><<<dim3(8, 32), 256, 0, stream>>>(
            actb, 2048, w2sb, 0, 0, 2048, outS, 1024, nullptr, 4096, 2048,
            nullptr, nullptr, nullptr, nullptr);
    } else if (avail >= MID_NEED) {
        // ========== MID: fast shared path + improved old routed path =======
        ushort* act   = (ushort*)(base + META);
        ushort* hidb  = act   + (size_t)8192 * 512;
        ushort* w13sb = hidb  + (size_t)4096 * 1024;
        ushort* w2sb  = w13sb + (size_t)4096 * 1024;

        to_bf16<<<1024, 256, 0, stream>>>(in0, in4, hidb,  (long)4096 * 1024 / 8, dflag, xsel);
        to_bf16<<<1024, 256, 0, stream>>>(in4, in0, w13sb, (long)4096 * 1024 / 8, dflag, xsel);
        to_bf16<<<1024, 256, 0, stream>>>(w2s, nullptr, w2sb, (long)1024 * 2048 / 8, dflag, xsel);

        gemm_nt<1,1,1,0,0,1,0,0><<<dim3(8, 64, NEXP), 256, 0, stream>>>(
            hidb, nullptr, 1024, w13, nullptr, UP_R, sB1, act, 512, nullptr, 0, 1024, 0,
            dflag, xsel, counts, offsets, pairinfo, pairw, 0, 0, T_TOK);
        gemm_nt<0,0,1,1,0,1,0,1><<<dim3(16, 64, NEXP), 256, 0, stream>>>(
            act, nullptr, 512, w2, nullptr, 0, sB2, outF, 1024, outS, 0, 512, 0,
            dflag, xsel, counts, offsets, pairinfo, pairw, 0, 0, T_TOK);
        add_kernel<<<(T_TOK * 1024 / 4 + 255) / 256, 256, 0, stream>>>(outF, outS, T_TOK * 1024 / 4);
        for (int c = 0; c < 2; ++c) {
            gemm_fast<1,0,0,0><<<dim3(32, 16), 256, 0, stream>>>(
                hidb + (size_t)c * 2048 * 1024, 1024, w13sb, UP_S, 0, 1024,
                act, 2048, nullptr, 2048, 1024, nullptr, nullptr, nullptr, nullptr);
            gemm_fast<0,0,0,0><<<dim3(8, 16), 256, 0, stream>>>(
                act, 2048, w2sb, 0, 0, 2048, outS + (size_t)c * 2048 * 1024, 1024, nullptr,
                2048, 2048, nullptr, nullptr, nullptr, nullptr);
        }
    } else {
        // ===================== fallback: original kernel ===================
        const size_t MB = 1024 * 1024;
        int grouped, Mcap, CH;
        if      (avail >= 8 * MB) { grouped = 1; Mcap = T_TOK; CH = 2048; }
        else if (avail >= 1 * MB) { grouped = 0; Mcap = 1024;  CH = 256;  }
        else                      { grouped = 0; Mcap = 256;   CH = 64;   }
        ushort* act = (ushort*)(base + META);

        if (grouped) {
            gemm_nt<1,1,1,0,0,0,0,0><<<dim3(8, 64, NEXP), 256, 0, stream>>>(
                in0, in4, 1024, w13, nullptr, UP_R, sB1, act, 512, nullptr, 0, 1024, 0,
                dflag, xsel, counts, offsets, pairinfo, pairw, 0, 0, T_TOK);
            gemm_nt<0,0,1,1,0,1,0,1><<<dim3(16, 64, NEXP), 256, 0, stream>>>(
                act, nullptr, 512, w2, nullptr, 0, sB2, outF, 1024, outS, 0, 512, 0,
                dflag, xsel, counts, offsets, pairinfo, pairw, 0, 0, T_TOK);
        } else {
            for (int e = 0; e < NEXP; ++e) {
                for (int mb = 0; mb < T_TOK; mb += Mcap) {
                    gemm_nt<1,1,1,0,1,0,0,0><<<dim3(8, Mcap / 64, 1), 256, 0, stream>>>(
                        in0, in4, 1024, w13, nullptr, UP_R, sB1, act, 512, nullptr, 0, 1024, 0,
                        dflag, xsel, counts, offsets, pairinfo, pairw, e, mb, Mcap);
                    gemm_nt<0,0,1,1,1,1,0,1><<<dim3(16, Mcap / 64, 1), 256, 0, stream>>>(
                        act, nullptr, 512, w2, nullptr, 0, sB2, outF, 1024, outS, 0, 512, 0,
                        dflag, xsel, counts, offsets, pairinfo, pairw, e, mb, Mcap);
                }
            }
        }
        add_kernel<<<(T_TOK * 1024 / 4 + 255) / 256, 256, 0, stream>>>(outF, outS, T_TOK * 1024 / 4);
        for (int c = 0; c < T_TOK / CH; ++c) {
            gemm_nt<1,0,0,0,0,0,0,0><<<dim3(2048 / 64, CH / 64), 256, 0, stream>>>(
                in0, in4, 1024, in4, in0, UP_S, 0, act, 2048, nullptr, CH, 1024, c * CH,
                dflag, xsel, nullptr, nullptr, nullptr, nullptr, 0, 0, 0);
            gemm_nt<0,0,0,0,0,1,0,1><<<dim3(1024 / 64, CH / 64), 256, 0, stream>>>(
                act, nullptr, 2048, w2s, nullptr, 0, 0,
                outS + (size_t)c * CH * 1024, 1024, nullptr, CH, 2048, 0,
                dflag, xsel, nullptr, nullptr, nullptr, nullptr, 0, 0, 0);
        }
    }
    (void)in_sizes; (void)n_in; (void)out_size;
}

// Round 5
// 412.025 us; speedup vs baseline: 1.4275x; 1.0772x over previous
//
#include <hip/hip_runtime.h>

// ---------------------------------------------------------------------------
// SharedFusedMoE on MI355X (gfx950). fp32 inputs, FP32 outputs.
// T=4096, D=1024, I=512 (routed), E=16, top-2, SI=2048 (shared).
// Round 11: g2 rebalance. Round-4 counters showed g2_fused at 113us with
// Occupancy 7.8% / MfmaUtil 9% -- the shared-w2 slice had only 256 blocks
// (1/CU) each running K=2048, a 4x-duration tail after the routed blocks
// retire. Fix: shared-w2 becomes BN=64 (NARROW core) x split-K=2 (halves to
// outS / new outP partial, reduced in the final add) => 1024 blocks, 4/CU
// tail. FULL3 tier (+16MB); FULL2 path kept verbatim as fallback.
// T2 swizzle retained (bank conflicts measured 0 in round 4).
// Output slot 0 = shared_out, slot 1 = fused_out (reference return order).
// ---------------------------------------------------------------------------

#define T_TOK 4096
#define NEXP  16

typedef __attribute__((ext_vector_type(8))) short   short8;   // 8 x bf16
typedef __attribute__((ext_vector_type(4))) float   floatx4;  // MFMA acc

typedef __attribute__((address_space(1))) void as1_void;
typedef __attribute__((address_space(3))) void as3_void;

__device__ __forceinline__ float bf2f(ushort u) {
    union { unsigned int i; float f; } v; v.i = ((unsigned int)u) << 16; return v.f;
}
__device__ __forceinline__ ushort f2bf(float f) {   // RNE, finite inputs
    unsigned int u = __builtin_bit_cast(unsigned int, f);
    unsigned int r = 0x7FFFu + ((u >> 16) & 1u);
    return (ushort)((u + r) >> 16);
}

__device__ __forceinline__ float load_elem(const void* p, long i, int bf) {
    return bf ? bf2f(((const ushort*)p)[i]) : ((const float*)p)[i];
}

// dtype probe (insurance): even ushort indices are real bf16 values
// (clustered exponent) if bf16 input, fp32 low-mantissa noise if fp32.
__global__ void detect_dtype(const ushort* __restrict__ xu, int* __restrict__ dflag) {
    __shared__ int cnt;
    if (threadIdx.x == 0) cnt = 0;
    __syncthreads();
    int ok = 0;
    for (int i = threadIdx.x; i < 512; i += 256) {
        int e = (xu[2 * i] >> 7) & 0xFF;
        ok += (e >= 90 && e <= 140) ? 1 : 0;
    }
    atomicAdd(&cnt, ok);
    __syncthreads();
    if (threadIdx.x == 0) *dflag = (cnt >= 384) ? 1 : 0;   // 1 = bf16, 0 = fp32
}

// scale probe (insurance): hidden_states std 1.0 vs w13_shared std 1/32.
__global__ void detect_xsel(const void* __restrict__ p0, const void* __restrict__ p4,
                            const int* __restrict__ dflag, int* __restrict__ xsel) {
    __shared__ float s0s, s4s;
    if (threadIdx.x == 0) { s0s = 0.f; s4s = 0.f; }
    __syncthreads();
    int bf = *dflag;
    float a0 = 0.f, a4 = 0.f;
    for (int i = threadIdx.x; i < 4096; i += 256) {
        a0 += fabsf(load_elem(p0, (long)i * 997 + 13, bf));
        a4 += fabsf(load_elem(p4, (long)i * 997 + 13, bf));
    }
    atomicAdd(&s0s, a0);
    atomicAdd(&s4s, a4);
    __syncthreads();
    if (threadIdx.x == 0) *xsel = (s0s >= s4s) ? 0 : 1;
}

// Router: softmax -> top-2 -> renormalize (denominators cancel).
__device__ __forceinline__ void top2(const void* logits, int t, int bf,
                                     int& b0, int& b1, float& w0, float& w1) {
    float l[16];
#pragma unroll
    for (int j = 0; j < 16; ++j) l[j] = load_elem(logits, t * 16 + j, bf);
    b0 = 0; float v0 = l[0];
#pragma unroll
    for (int j = 1; j < 16; ++j) { if (l[j] > v0) { v0 = l[j]; b0 = j; } }
    b1 = -1; float v1 = -3.4e38f;
#pragma unroll
    for (int j = 0; j < 16; ++j) {
        if (j == b0) continue;
        if (l[j] > v1) { v1 = l[j]; b1 = j; }
    }
    float d = __expf(v1 - v0);
    w0 = 1.0f / (1.0f + d);
    w1 = d / (1.0f + d);
}

__global__ void router_counts(const void* __restrict__ logits, const int* __restrict__ dflag,
                              int* __restrict__ counts) {
    int t = blockIdx.x * blockDim.x + threadIdx.x;
    if (t >= T_TOK) return;
    int b0, b1; float w0, w1;
    top2(logits, t, *dflag, b0, b1, w0, w1);
    atomicAdd(&counts[b0], 1);
    atomicAdd(&counts[b1], 1);
}

__global__ void scan_kernel(const int* __restrict__ counts, int* __restrict__ offsets) {
    if (threadIdx.x == 0 && blockIdx.x == 0) {
        int acc = 0;
        for (int e = 0; e < NEXP; ++e) { offsets[e] = acc; acc += counts[e]; }
    }
}

__global__ void router_pairs(const void* __restrict__ logits, const int* __restrict__ dflag,
                             const int* __restrict__ offsets, int* __restrict__ cursor,
                             int* __restrict__ pairinfo, float* __restrict__ pairw) {
    int t = blockIdx.x * blockDim.x + threadIdx.x;
    if (t >= T_TOK) return;
    int b0, b1; float w0, w1;
    top2(logits, t, *dflag, b0, b1, w0, w1);
    int p0 = offsets[b0] + atomicAdd(&cursor[b0], 1);
    pairinfo[p0] = 2 * t;     pairw[p0] = w0;
    int p1 = offsets[b1] + atomicAdd(&cursor[b1], 1);
    pairinfo[p1] = 2 * t + 1; pairw[p1] = w1;
}

// ---------------------------------------------------------------------------
// One-shot fp32 -> bf16 conversion (memory-bound, 16B stores).
// ---------------------------------------------------------------------------
__global__ void to_bf16(const void* __restrict__ pA, const void* __restrict__ pB,
                        ushort* __restrict__ dst, long n8,
                        const int* __restrict__ dflag, const int* __restrict__ xsel)
{
    const void* src = (pB != nullptr && *xsel) ? pB : pA;
    const int bf = *dflag;
    long i = (long)blockIdx.x * blockDim.x + threadIdx.x;
    const long stride = (long)gridDim.x * blockDim.x;
    for (; i < n8; i += stride) {
        uint4 v;
        if (bf) {
            v = ((const uint4*)src)[i];
        } else {
            float4 f0 = ((const float4*)src)[i * 2];
            float4 f1 = ((const float4*)src)[i * 2 + 1];
            v.x = (unsigned)f2bf(f0.x) | ((unsigned)f2bf(f0.y) << 16);
            v.y = (unsigned)f2bf(f0.z) | ((unsigned)f2bf(f0.w) << 16);
            v.z = (unsigned)f2bf(f1.x) | ((unsigned)f2bf(f1.y) << 16);
            v.w = (unsigned)f2bf(f1.z) | ((unsigned)f2bf(f1.w) << 16);
        }
        ((uint4*)dst)[i] = v;
    }
}

// ---------------------------------------------------------------------------
// m97-class bf16 NT GEMM core. 128-row tile, BK=64, 256 thr = 4 waves (2x2).
// Plain: BN=128, wave = 4x4 frags of 16x16x32. SWIGLU: BN=64 (gate+up tiles),
// wave = 4x2 + 4x2 frags. NARROW: BN=64 single-matrix (shared-w2 split-K).
// T2 swizzle (rule #21): global_load_lds writes linearly (lane*16B); the
// per-lane GLOBAL source column group is c8 = (lane&7) ^ (lane>>3), so LDS
// physical 16B-slot s of row R holds logical col-group s ^ (R&7). Fragment
// reads use slot ((kc*4+quad) ^ (r16&7)) -> each 8-lane phase covers 8
// distinct slots (all 32 banks) -> conflict-free. Involution both sides.
// Frag maps: A/B lane L elem j -> row (L&15), k=(L>>4)*8+j; C/D col=L&15,
// row=(L>>4)*4+reg.  (Bank conflicts measured 0 in round 4.)
// ---------------------------------------------------------------------------
__device__ __forceinline__ void gload16(const ushort* g, ushort* l) {
    __builtin_amdgcn_global_load_lds((as1_void*)g, (as3_void*)l, 16, 0, 0);
}

template <int SWIGLU, int GATHER, int ROUTED, int SCATTER, int NARROW = 0>
__device__ __forceinline__ void gemm_core(
    ushort* __restrict__ smem,
    const ushort* __restrict__ A, int lda,
    const ushort* __restrict__ B0, long upoff, long bbase, int ldb,
    void* __restrict__ C, int ldc, float* __restrict__ C2,
    int m0, int n0, int Mloc, int K, int pair_base,
    const int* __restrict__ pairinfo, const float* __restrict__ pairw)
{
    constexpr int BNRW = (SWIGLU || NARROW);   // 64-wide B tile
    constexpr int NBI = BNRW ? 2 : 4;     // B-stage instrs per wave per K-step
    constexpr int NFN = BNRW ? 2 : 4;     // 16-col frags per wave

    ushort* As  = smem;                       // 128 x 64
    ushort* Bs0 = smem + 128 * 64;            // BN x 64
    ushort* Bs1 = SWIGLU ? (smem + 128 * 64 + 64 * 64) : nullptr;

    const int tid  = threadIdx.x;
    const int lane = tid & 63;
    const int wave = tid >> 6;
    const int srow = lane >> 3;                      // row within 8-row group
    const int scol = ((lane & 7) ^ srow) * 8;        // swizzled source col grp

    long aoff[4];
#pragma unroll
    for (int i = 0; i < 4; ++i) {
        int rl  = m0 + (wave * 4 + i) * 8 + srow;
        int rlc = rl < Mloc ? rl : Mloc - 1;
        long gr;
        if (GATHER)      gr = (long)(pairinfo[pair_base + rlc] >> 1);
        else if (ROUTED) gr = pair_base + rlc;
        else             gr = rlc;
        aoff[i] = gr * (long)lda + scol;
    }
    long boff[NBI];
#pragma unroll
    for (int i = 0; i < NBI; ++i) {
        int r = (wave * NBI + i) * 8 + srow;
        boff[i] = bbase + (long)(n0 + r) * ldb + scol;
    }

    const int wm   = (wave >> 1) * 64;
    const int wn   = (wave & 1) * (BNRW ? 32 : 64);
    const int r16  = lane & 15;
    const int quad = lane >> 4;
    const int rlow = r16 & 7;

    const floatx4 z4 = {0.f, 0.f, 0.f, 0.f};
    floatx4 accg[4][NFN], accu[4][NFN];
#pragma unroll
    for (int mi = 0; mi < 4; ++mi)
#pragma unroll
        for (int ni = 0; ni < NFN; ++ni) { accg[mi][ni] = z4; accu[mi][ni] = z4; }

    for (int k0 = 0; k0 < K; k0 += 64) {
#pragma unroll
        for (int i = 0; i < 4; ++i)
            gload16(A + aoff[i] + k0, &As[(wave * 4 + i) * 512]);
#pragma unroll
        for (int i = 0; i < NBI; ++i) {
            gload16(B0 + boff[i] + k0, &Bs0[(wave * NBI + i) * 512]);
            if constexpr (SWIGLU)
                gload16(B0 + boff[i] + upoff + k0, &Bs1[(wave * NBI + i) * 512]);
        }
        __syncthreads();   // compiler drains vmcnt before s_barrier
#pragma unroll
        for (int kc = 0; kc < 2; ++kc) {
            const int sw = ((kc * 4 + quad) ^ rlow) * 8;   // swizzled 16B slot
            short8 af[4];
#pragma unroll
            for (int mi = 0; mi < 4; ++mi)
                af[mi] = *(const short8*)&As[(wm + mi * 16 + r16) * 64 + sw];
            short8 bfr[NFN], ufr[NFN];
#pragma unroll
            for (int ni = 0; ni < NFN; ++ni) {
                bfr[ni] = *(const short8*)&Bs0[(wn + ni * 16 + r16) * 64 + sw];
                if constexpr (SWIGLU)
                    ufr[ni] = *(const short8*)&Bs1[(wn + ni * 16 + r16) * 64 + sw];
            }
#pragma unroll
            for (int mi = 0; mi < 4; ++mi)
#pragma unroll
                for (int ni = 0; ni < NFN; ++ni) {
                    accg[mi][ni] = __builtin_amdgcn_mfma_f32_16x16x32_bf16(
                        af[mi], bfr[ni], accg[mi][ni], 0, 0, 0);
                    if constexpr (SWIGLU)
                        accu[mi][ni] = __builtin_amdgcn_mfma_f32_16x16x32_bf16(
                            af[mi], ufr[ni], accu[mi][ni], 0, 0, 0);
                }
        }
        __syncthreads();
    }

#pragma unroll
    for (int mi = 0; mi < 4; ++mi) {
#pragma unroll
        for (int r = 0; r < 4; ++r) {
            const int grow = m0 + wm + mi * 16 + quad * 4 + r;
            if (grow >= Mloc) continue;
            int info = 0; float w = 0.f;
            if constexpr (SCATTER) {
                const int p = pair_base + grow;
                info = pairinfo[p]; w = pairw[p];
            }
#pragma unroll
            for (int ni = 0; ni < NFN; ++ni) {
                const int col = n0 + wn + ni * 16 + r16;
                float val;
                if constexpr (SWIGLU) {
                    float g = accg[mi][ni][r];
                    float u = accu[mi][ni][r];
                    val = (g / (1.0f + __expf(-g))) * u;   // silu(g)*u
                } else {
                    val = accg[mi][ni][r];
                }
                if constexpr (SCATTER) {
                    long idx = (long)(info >> 1) * 1024 + col;
                    float* dst = (info & 1) ? C2 : (float*)C;
                    dst[idx] = w * val;
                } else if constexpr (SWIGLU) {
                    long crow = ROUTED ? (long)(pair_base + grow) : (long)grow;
                    ((ushort*)C)[crow * ldc + col] = f2bf(val);   // bf16 act
                } else {
                    ((float*)C)[(long)grow * ldc + col] = val;    // fp32 out
                }
            }
        }
    }
}

// Thin wrapper (MID tier + non-fused FULL fallback keep this entry point).
template <int SWIGLU, int GATHER, int ROUTED, int SCATTER>
__global__ __launch_bounds__(256)
void gemm_fast(const ushort* __restrict__ A, int lda,
               const ushort* __restrict__ B0, long upoff, long strideB, int ldb,
               void* __restrict__ C, int ldc, float* __restrict__ C2,
               int M, int K,
               const int* __restrict__ counts, const int* __restrict__ offsets,
               const int* __restrict__ pairinfo, const float* __restrict__ pairw)
{
    __shared__ __align__(16) ushort smem[16384];
    const int e    = ROUTED ? (int)blockIdx.z : 0;
    const int Mloc = ROUTED ? counts[e] : M;
    const int m0   = blockIdx.y * 128;
    if (m0 >= Mloc) return;
    constexpr int BN = SWIGLU ? 64 : 128;
    const int n0  = blockIdx.x * BN;
    const int pb  = ROUTED ? offsets[e] : 0;
    const long bb = ROUTED ? (long)e * strideB : 0L;
    gemm_core<SWIGLU, GATHER, ROUTED, SCATTER>(
        smem, A, lda, B0, upoff, bb, ldb, C, ldc, C2,
        m0, n0, Mloc, K, pb, pairinfo, pairw);
}

// Fused L1: routed w13-SwiGLU (z<4, 4 experts per z-slice) + shared w13-SwiGLU
// (z==4). Grid (32, 32, 5).
__global__ __launch_bounds__(256)
void g1_fused(const ushort* __restrict__ hidb, const ushort* __restrict__ w13b,
              const ushort* __restrict__ w13sb,
              ushort* __restrict__ actR, ushort* __restrict__ actS,
              const int* __restrict__ counts, const int* __restrict__ offsets,
              const int* __restrict__ pairinfo)
{
    __shared__ __align__(16) ushort smem[16384];
    const int z  = blockIdx.z;
    const int m0 = blockIdx.y * 128;
    if (z < 4) {
        const int e    = z * 4 + ((int)blockIdx.x >> 3);
        const int Mloc = counts[e];
        if (m0 >= Mloc) return;
        const int n0 = ((int)blockIdx.x & 7) * 64;
        gemm_core<1, 1, 1, 0>(smem, hidb, 1024,
                              w13b, (long)512 * 1024, (long)e * 1024 * 1024, 1024,
                              actR, 512, nullptr,
                              m0, n0, Mloc, 1024, offsets[e], pairinfo, nullptr);
    } else {
        const int n0 = (int)blockIdx.x * 64;
        gemm_core<1, 0, 0, 0>(smem, hidb, 1024,
                              w13sb, (long)2048 * 1024, 0L, 1024,
                              actS, 2048, nullptr,
                              m0, n0, T_TOK, 1024, 0, nullptr, nullptr);
    }
}

// Fused L2: routed w2 + scatter (rank0->outF, rank1->outT) (z<4) + shared w2.
// SPLIT=1: shared part is BN=64, split-K=2 (z=4 -> outS half-K, z=5 -> outP
// half-K); grid (32, 32, 6). SPLIT=0: legacy full-K z==4; grid (32, 32, 5).
template <int SPLIT>
__global__ __launch_bounds__(256)
void g2_fused(const ushort* __restrict__ actR, const ushort* __restrict__ actS,
              const ushort* __restrict__ w2b, const ushort* __restrict__ w2sb,
              float* __restrict__ outF, float* __restrict__ outT,
              float* __restrict__ outS, float* __restrict__ outP,
              const int* __restrict__ counts, const int* __restrict__ offsets,
              const int* __restrict__ pairinfo, const float* __restrict__ pairw)
{
    __shared__ __align__(16) ushort smem[16384];
    const int z  = blockIdx.z;
    const int m0 = blockIdx.y * 128;
    if (z < 4) {
        const int e    = z * 4 + ((int)blockIdx.x >> 3);
        const int Mloc = counts[e];
        if (m0 >= Mloc) return;
        const int n0 = ((int)blockIdx.x & 7) * 128;
        gemm_core<0, 0, 1, 1>(smem, actR, 512,
                              w2b, 0L, (long)e * 1024 * 512, 512,
                              outF, 1024, outT,
                              m0, n0, Mloc, 512, offsets[e], pairinfo, pairw);
    } else if constexpr (SPLIT) {
        const int zz = z - 4;                 // K-half index
        if ((int)blockIdx.x >= 16) return;
        const int n0 = (int)blockIdx.x * 64;
        gemm_core<0, 0, 0, 0, 1>(smem, actS + zz * 1024, 2048,
                                 w2sb + zz * 1024, 0L, 0L, 2048,
                                 zz ? outP : outS, 1024, nullptr,
                                 m0, n0, T_TOK, 1024, 0, nullptr, nullptr);
    } else {
        if ((int)blockIdx.x >= 8) return;
        const int n0 = (int)blockIdx.x * 128;
        gemm_core<0, 0, 0, 0>(smem, actS, 2048,
                              w2sb, 0L, 0L, 2048,
                              outS, 1024, nullptr,
                              m0, n0, T_TOK, 2048, 0, nullptr, nullptr);
    }
}

// ---------------------------------------------------------------------------
// Fallback GEMM (original session kernel, verbatim) — tiny-ws insurance.
// ---------------------------------------------------------------------------
__device__ __forceinline__ void stage8(const void* __restrict__ src, long eoff, int bf,
                                       ushort* __restrict__ dst) {
    if (bf) {
        *(uint4*)dst = *(const uint4*)((const ushort*)src + eoff);
    } else {
        const float* s = (const float*)src + eoff;
        float4 f0 = *(const float4*)s;
        float4 f1 = *(const float4*)(s + 4);
        uint4 v;
        v.x = (unsigned)f2bf(f0.x) | ((unsigned)f2bf(f0.y) << 16);
        v.y = (unsigned)f2bf(f0.z) | ((unsigned)f2bf(f0.w) << 16);
        v.z = (unsigned)f2bf(f1.x) | ((unsigned)f2bf(f1.y) << 16);
        v.w = (unsigned)f2bf(f1.z) | ((unsigned)f2bf(f1.w) << 16);
        *(uint4*)dst = v;
    }
}

template <int SWIGLU, int GATHER, int ROUTED, int SCATTER, int LOCAL,
          int A_DT, int B_DT, int C_F32>
__global__ __launch_bounds__(256)
void gemm_nt(const void* __restrict__ A, const void* __restrict__ Aalt, int lda,
             const void* __restrict__ B0, const void* __restrict__ B0alt,
             long upoff, long strideB,
             void* __restrict__ C, int ldc, void* __restrict__ C2,
             int M, int K, int row0,
             const int* __restrict__ dflag, const int* __restrict__ xsel,
             const int* __restrict__ counts, const int* __restrict__ offsets,
             const int* __restrict__ pairinfo, const float* __restrict__ pairw,
             int e_base, int m_base, int Mcap)
{
    const int dfl = (A_DT && B_DT) ? 1 : *dflag;
    const int abf = A_DT ? 1 : dfl;
    const int bbf = B_DT ? 1 : dfl;
    if (Aalt  && *xsel) A  = Aalt;
    if (B0alt && *xsel) B0 = B0alt;

    const int e = ROUTED ? (e_base + (int)blockIdx.z) : 0;
    int Mloc;
    if (ROUTED) {
        int avail = counts[e] - m_base;
        Mloc = avail < Mcap ? avail : Mcap;
    } else {
        Mloc = M;
    }
    const int m0 = blockIdx.y * 64;
    if (m0 >= Mloc) return;
    const int n0 = blockIdx.x * 64;
    const int pair_base = ROUTED ? (offsets[e] + m_base) : 0;
    const int abase     = ROUTED ? (LOCAL ? 0 : offsets[e]) : 0;
    const long bbase    = ROUTED ? (long)e * strideB : 0L;

    constexpr int LS = 72;
    __shared__ __align__(16) ushort As[64 * LS];
    __shared__ __align__(16) ushort Bs0[64 * LS];
    __shared__ __align__(16) ushort Bs1[SWIGLU ? 64 * LS : 8];

    const int tid = threadIdx.x;

    int  lofs[2];
    long aoff[2], boff[2];
#pragma unroll
    for (int i = 0; i < 2; ++i) {
        int idx = tid + i * 256;
        int row = idx >> 3;
        int col = (idx & 7) * 8;
        lofs[i] = row * LS + col;
        int rl  = m0 + row;
        int rlc = rl < Mloc ? rl : (Mloc - 1);
        long rA;
        if (GATHER)      rA = (long)(pairinfo[pair_base + rlc] >> 1);
        else if (ROUTED) rA = abase + rlc;
        else             rA = row0 + rl;
        aoff[i] = rA * (long)lda + col;
        boff[i] = bbase + (long)(n0 + row) * K + col;
    }

    const int lane = tid & 63;
    const int wave = tid >> 6;
    const int wm   = (wave >> 1) * 32;
    const int wn   = (wave & 1) * 32;
    const int r16  = lane & 15;
    const int quad = lane >> 4;

    floatx4 accg[2][2] = {{{0.f,0.f,0.f,0.f},{0.f,0.f,0.f,0.f}},{{0.f,0.f,0.f,0.f},{0.f,0.f,0.f,0.f}}};
    floatx4 accu[2][2] = {{{0.f,0.f,0.f,0.f},{0.f,0.f,0.f,0.f}},{{0.f,0.f,0.f,0.f},{0.f,0.f,0.f,0.f}}};

    for (int k0 = 0; k0 < K; k0 += 64) {
#pragma unroll
        for (int i = 0; i < 2; ++i) {
            stage8(A,  aoff[i] + k0, abf, &As[lofs[i]]);
            stage8(B0, boff[i] + k0, bbf, &Bs0[lofs[i]]);
            if (SWIGLU) stage8(B0, boff[i] + k0 + upoff, bbf, &Bs1[lofs[i]]);
        }
        __syncthreads();
#pragma unroll
        for (int kc = 0; kc < 2; ++kc) {
            const int kof = kc * 32 + quad * 8;
            short8 a0 = *(const short8*)&As[(wm + r16)      * LS + kof];
            short8 a1 = *(const short8*)&As[(wm + 16 + r16) * LS + kof];
            short8 b0 = *(const short8*)&Bs0[(wn + r16)      * LS + kof];
            short8 b1 = *(const short8*)&Bs0[(wn + 16 + r16) * LS + kof];
            accg[0][0] = __builtin_amdgcn_mfma_f32_16x16x32_bf16(a0, b0, accg[0][0], 0, 0, 0);
            accg[0][1] = __builtin_amdgcn_mfma_f32_16x16x32_bf16(a0, b1, accg[0][1], 0, 0, 0);
            accg[1][0] = __builtin_amdgcn_mfma_f32_16x16x32_bf16(a1, b0, accg[1][0], 0, 0, 0);
            accg[1][1] = __builtin_amdgcn_mfma_f32_16x16x32_bf16(a1, b1, accg[1][1], 0, 0, 0);
            if (SWIGLU) {
                short8 u0 = *(const short8*)&Bs1[(wn + r16)      * LS + kof];
                short8 u1 = *(const short8*)&Bs1[(wn + 16 + r16) * LS + kof];
                accu[0][0] = __builtin_amdgcn_mfma_f32_16x16x32_bf16(a0, u0, accu[0][0], 0, 0, 0);
                accu[0][1] = __builtin_amdgcn_mfma_f32_16x16x32_bf16(a0, u1, accu[0][1], 0, 0, 0);
                accu[1][0] = __builtin_amdgcn_mfma_f32_16x16x32_bf16(a1, u0, accu[1][0], 0, 0, 0);
                accu[1][1] = __builtin_amdgcn_mfma_f32_16x16x32_bf16(a1, u1, accu[1][1], 0, 0, 0);
            }
        }
        __syncthreads();
    }

#pragma unroll
    for (int mi = 0; mi < 2; ++mi) {
#pragma unroll
        for (int ni = 0; ni < 2; ++ni) {
#pragma unroll
            for (int r = 0; r < 4; ++r) {
                int rowl = wm + mi * 16 + quad * 4 + r;
                int grow = m0 + rowl;
                if (grow < Mloc) {
                    int col = n0 + wn + ni * 16 + r16;
                    float g = accg[mi][ni][r];
                    float val;
                    if (SWIGLU) {
                        float u = accu[mi][ni][r];
                        val = (g / (1.0f + __expf(-g))) * u;
                    } else {
                        val = g;
                    }
                    if (SCATTER) {
                        int p    = pair_base + grow;
                        int info = pairinfo[p];
                        float w  = pairw[p];
                        long idx = (long)(info >> 1) * 1024 + col;
                        void* dst = (info & 1) ? C2 : C;
                        if (C_F32) ((float*)dst)[idx]  = w * val;
                        else       ((ushort*)dst)[idx] = f2bf(w * val);
                    } else {
                        int crow = ROUTED ? (abase + grow) : grow;
                        long idx = (long)crow * ldc + col;
                        if (C_F32) ((float*)C)[idx]  = val;
                        else       ((ushort*)C)[idx] = f2bf(val);
                    }
                }
            }
        }
    }
}

// outF[i] += outT[i]   (fp32, 4 elems/thread)
__global__ void add_kernel(float* __restrict__ outF, const float* __restrict__ outT, int n4) {
    int i = blockIdx.x * blockDim.x + threadIdx.x;
    if (i >= n4) return;
    float4 a = *(const float4*)(outF + (long)i * 4);
    float4 b = *(const float4*)(outT + (long)i * 4);
    a.x += b.x; a.y += b.y; a.z += b.z; a.w += b.w;
    *(float4*)(outF + (long)i * 4) = a;
}

// Fused reductions: outF += outT (fused rank1) and outS += outP (shared K-half).
__global__ void add2_kernel(float* __restrict__ outF, const float* __restrict__ outT,
                            float* __restrict__ outS, const float* __restrict__ outP,
                            int n4) {
    int i = blockIdx.x * blockDim.x + threadIdx.x;
    if (i < n4) {
        float4 a = *(const float4*)(outF + (long)i * 4);
        float4 b = *(const float4*)(outT + (long)i * 4);
        a.x += b.x; a.y += b.y; a.z += b.z; a.w += b.w;
        *(float4*)(outF + (long)i * 4) = a;
    } else if (i < 2 * n4) {
        int j = i - n4;
        float4 a = *(const float4*)(outS + (long)j * 4);
        float4 b = *(const float4*)(outP + (long)j * 4);
        a.x += b.x; a.y += b.y; a.z += b.z; a.w += b.w;
        *(float4*)(outS + (long)j * 4) = a;
    }
}

// ---------------------------------------------------------------------------
extern "C" void kernel_launch(void* const* d_in, const int* in_sizes, int n_in,
                              void* d_out, int out_size, void* d_ws, size_t ws_size,
                              hipStream_t stream)
{
    const void* in0  = d_in[0];  // hidden_states [4096,1024] fp32
    const void* rl   = d_in[1];  // router_logits [4096,16]
    const void* w13  = d_in[2];  // [16,1024,1024]
    const void* w2   = d_in[3];  // [16,1024,512]
    const void* in4  = d_in[4];  // w13_shared [4096,1024]
    const void* w2s  = d_in[5];  // w2_shared [1024,2048]
    float* outS = (float*)d_out;                          // shared (final)
    float* outF = (float*)d_out + (size_t)T_TOK * 1024;   // fused (final)

    // ---- metadata layout (66 KB) ----
    char*  base     = (char*)d_ws;
    int*   counts   = (int*)(base);
    int*   cursor   = (int*)(base + 64);
    int*   dflag    = (int*)(base + 128);
    int*   xsel     = (int*)(base + 132);
    int*   offsets  = (int*)(base + 192);
    int*   pairinfo = (int*)(base + 256);
    float* pairw    = (float*)(base + 256 + 32768);
    const size_t META = 256 + 65536;

    size_t avail = ws_size > META ? ws_size - META : 0;

    // ---- probes + routing (common) ----
    detect_dtype<<<1, 256, 0, stream>>>((const ushort*)in0, dflag);
    detect_xsel<<<1, 256, 0, stream>>>(in0, in4, dflag, xsel);
    hipMemsetAsync(counts, 0, 128, stream);    // counts + cursor
    router_counts<<<T_TOK / 256, 256, 0, stream>>>(rl, dflag, counts);
    scan_kernel<<<1, 64, 0, stream>>>(counts, offsets);
    router_pairs<<<T_TOK / 256, 256, 0, stream>>>(rl, dflag, offsets, cursor, pairinfo, pairw);

    const long sB1  = (long)1024 * 1024;   // w13 per-expert elements
    const long sB2  = (long)1024 * 512;    // w2 per-expert elements
    const long UP_R = (long)512 * 1024;    // routed up-offset within expert block
    const long UP_S = (long)2048 * 1024;   // shared up-offset in w13s

    const size_t FULL3_NEED = 113246208ULL; // FULL2 + 16MB outP (split-K partial)
    const size_t FULL2_NEED = 96468992ULL;  // all-bf16 + actR + actS (outT aliases hidb+w13sb)
    const size_t FULL_NEED  = 88080384ULL;  // all-bf16 + single shared act
    const size_t MID_NEED   = 29360128ULL;  // act + hid + w13s + w2s bf16

    if (avail >= FULL2_NEED) {
        // ============ FULL2/3: bf16 everywhere + fused launches ===========
        ushort* hidb  = (ushort*)(base + META);
        ushort* w13sb = hidb  + (size_t)4096 * 1024;
        ushort* w13b  = w13sb + (size_t)4096 * 1024;
        ushort* w2b   = w13b  + (size_t)16 * 1024 * 1024;
        ushort* w2sb  = w2b   + (size_t)16 * 1024 * 512;
        ushort* actR  = w2sb  + (size_t)1024 * 2048;     // [8192, 512] bf16
        ushort* actS  = actR  + (size_t)8192 * 512;      // [4096, 2048] bf16
        float*  outP  = (float*)(actS + (size_t)4096 * 2048);  // FULL3 only
        float*  outT  = (float*)hidb;   // rank1 temp; aliases hidb+w13sb (dead after g1)

        to_bf16<<<1024, 256, 0, stream>>>(in0, in4, hidb,  (long)4096 * 1024 / 8,      dflag, xsel);
        to_bf16<<<1024, 256, 0, stream>>>(in4, in0, w13sb, (long)4096 * 1024 / 8,      dflag, xsel);
        to_bf16<<<1024, 256, 0, stream>>>(w13, nullptr, w13b, (long)16 * 1024 * 1024 / 8, dflag, xsel);
        to_bf16<<<1024, 256, 0, stream>>>(w2,  nullptr, w2b,  (long)16 * 1024 * 512 / 8,  dflag, xsel);
        to_bf16<<<1024, 256, 0, stream>>>(w2s, nullptr, w2sb, (long)1024 * 2048 / 8,      dflag, xsel);

        g1_fused<<<dim3(32, 32, 5), 256, 0, stream>>>(
            hidb, w13b, w13sb, actR, actS, counts, offsets, pairinfo);

        if (avail >= FULL3_NEED) {
            g2_fused<1><<<dim3(32, 32, 6), 256, 0, stream>>>(
                actR, actS, w2b, w2sb, outF, outT, outS, outP,
                counts, offsets, pairinfo, pairw);
            add2_kernel<<<(2 * (T_TOK * 1024 / 4) + 255) / 256, 256, 0, stream>>>(
                outF, outT, outS, outP, T_TOK * 1024 / 4);
        } else {
            g2_fused<0><<<dim3(32, 32, 5), 256, 0, stream>>>(
                actR, actS, w2b, w2sb, outF, outT, outS, nullptr,
                counts, offsets, pairinfo, pairw);
            add_kernel<<<(T_TOK * 1024 / 4 + 255) / 256, 256, 0, stream>>>(
                outF, outT, T_TOK * 1024 / 4);
        }
    } else if (avail >= FULL_NEED) {
        // ====== FULL: bf16 everywhere, sequential launches (round-1) ======
        ushort* hidb  = (ushort*)(base + META);
        ushort* w13b  = hidb  + (size_t)4096 * 1024;
        ushort* w2b   = w13b  + (size_t)16 * 1024 * 1024;
        ushort* w13sb = w2b   + (size_t)16 * 1024 * 512;
        ushort* w2sb  = w13sb + (size_t)4096 * 1024;
        ushort* actb  = w2sb  + (size_t)1024 * 2048;

        to_bf16<<<1024, 256, 0, stream>>>(in0, in4, hidb,  (long)4096 * 1024 / 8,      dflag, xsel);
        to_bf16<<<1024, 256, 0, stream>>>(w13, nullptr, w13b, (long)16 * 1024 * 1024 / 8, dflag, xsel);
        to_bf16<<<1024, 256, 0, stream>>>(w2,  nullptr, w2b,  (long)16 * 1024 * 512 / 8,  dflag, xsel);
        to_bf16<<<1024, 256, 0, stream>>>(in4, in0, w13sb, (long)4096 * 1024 / 8,      dflag, xsel);
        to_bf16<<<1024, 256, 0, stream>>>(w2s, nullptr, w2sb, (long)1024 * 2048 / 8,      dflag, xsel);

        gemm_fast<1,1,1,0><<<dim3(8, 32, NEXP), 256, 0, stream>>>(
            hidb, 1024, w13b, UP_R, sB1, 1024, actb, 512, nullptr, 0, 1024,
            counts, offsets, pairinfo, pairw);
        gemm_fast<0,0,1,1><<<dim3(8, 32, NEXP), 256, 0, stream>>>(
            actb, 512, w2b, 0, sB2, 512, outF, 1024, outS, 0, 512,
            counts, offsets, pairinfo, pairw);
        add_kernel<<<(T_TOK * 1024 / 4 + 255) / 256, 256, 0, stream>>>(outF, outS, T_TOK * 1024 / 4);
        gemm_fast<1,0,0,0><<<dim3(32, 32), 256, 0, stream>>>(
            hidb, 1024, w13sb, UP_S, 0, 1024, actb, 2048, nullptr, 4096, 1024,
            nullptr, nullptr, nullptr, nullptr);
        gemm_fast<0,0,0,0><<<dim3(8, 32), 256, 0, stream>>>(
            actb, 2048, w2sb, 0, 0, 2048, outS, 1024, nullptr, 4096, 2048,
            nullptr, nullptr, nullptr, nullptr);
    } else if (avail >= MID_NEED) {
        // ========== MID: fast shared path + improved old routed path =======
        ushort* act   = (ushort*)(base + META);
        ushort* hidb  = act   + (size_t)8192 * 512;
        ushort* w13sb = hidb  + (size_t)4096 * 1024;
        ushort* w2sb  = w13sb + (size_t)4096 * 1024;

        to_bf16<<<1024, 256, 0, stream>>>(in0, in4, hidb,  (long)4096 * 1024 / 8, dflag, xsel);
        to_bf16<<<1024, 256, 0, stream>>>(in4, in0, w13sb, (long)4096 * 1024 / 8, dflag, xsel);
        to_bf16<<<1024, 256, 0, stream>>>(w2s, nullptr, w2sb, (long)1024 * 2048 / 8, dflag, xsel);

        gemm_nt<1,1,1,0,0,1,0,0><<<dim3(8, 64, NEXP), 256, 0, stream>>>(
            hidb, nullptr, 1024, w13, nullptr, UP_R, sB1, act, 512, nullptr, 0, 1024, 0,
            dflag, xsel, counts, offsets, pairinfo, pairw, 0, 0, T_TOK);
        gemm_nt<0,0,1,1,0,1,0,1><<<dim3(16, 64, NEXP), 256, 0, stream>>>(
            act, nullptr, 512, w2, nullptr, 0, sB2, outF, 1024, outS, 0, 512, 0,
            dflag, xsel, counts, offsets, pairinfo, pairw, 0, 0, T_TOK);
        add_kernel<<<(T_TOK * 1024 / 4 + 255) / 256, 256, 0, stream>>>(outF, outS, T_TOK * 1024 / 4);
        for (int c = 0; c < 2; ++c) {
            gemm_fast<1,0,0,0><<<dim3(32, 16), 256, 0, stream>>>(
                hidb + (size_t)c * 2048 * 1024, 1024, w13sb, UP_S, 0, 1024,
                act, 2048, nullptr, 2048, 1024, nullptr, nullptr, nullptr, nullptr);
            gemm_fast<0,0,0,0><<<dim3(8, 16), 256, 0, stream>>>(
                act, 2048, w2sb, 0, 0, 2048, outS + (size_t)c * 2048 * 1024, 1024, nullptr,
                2048, 2048, nullptr, nullptr, nullptr, nullptr);
        }
    } else {
        // ===================== fallback: original kernel ===================
        const size_t MB = 1024 * 1024;
        int grouped, Mcap, CH;
        if      (avail >= 8 * MB) { grouped = 1; Mcap = T_TOK; CH = 2048; }
        else if (avail >= 1 * MB) { grouped = 0; Mcap = 1024;  CH = 256;  }
        else                      { grouped = 0; Mcap = 256;   CH = 64;   }
        ushort* act = (ushort*)(base + META);

        if (grouped) {
            gemm_nt<1,1,1,0,0,0,0,0><<<dim3(8, 64, NEXP), 256, 0, stream>>>(
                in0, in4, 1024, w13, nullptr, UP_R, sB1, act, 512, nullptr, 0, 1024, 0,
                dflag, xsel, counts, offsets, pairinfo, pairw, 0, 0, T_TOK);
            gemm_nt<0,0,1,1,0,1,0,1><<<dim3(16, 64, NEXP), 256, 0, stream>>>(
                act, nullptr, 512, w2, nullptr, 0, sB2, outF, 1024, outS, 0, 512, 0,
                dflag, xsel, counts, offsets, pairinfo, pairw, 0, 0, T_TOK);
        } else {
            for (int e = 0; e < NEXP; ++e) {
                for (int mb = 0; mb < T_TOK; mb += Mcap) {
                    gemm_nt<1,1,1,0,1,0,0,0><<<dim3(8, Mcap / 64, 1), 256, 0, stream>>>(
                        in0, in4, 1024, w13, nullptr, UP_R, sB1, act, 512, nullptr, 0, 1024, 0,
                        dflag, xsel, counts, offsets, pairinfo, pairw, e, mb, Mcap);
                    gemm_nt<0,0,1,1,1,1,0,1><<<dim3(16, Mcap / 64, 1), 256, 0, stream>>>(
                        act, nullptr, 512, w2, nullptr, 0, sB2, outF, 1024, outS, 0, 512, 0,
                        dflag, xsel, counts, offsets, pairinfo, pairw, e, mb, Mcap);
                }
            }
        }
        add_kernel<<<(T_TOK * 1024 / 4 + 255) / 256, 256, 0, stream>>>(outF, outS, T_TOK * 1024 / 4);
        for (int c = 0; c < T_TOK / CH; ++c) {
            gemm_nt<1,0,0,0,0,0,0,0><<<dim3(2048 / 64, CH / 64), 256, 0, stream>>>(
                in0, in4, 1024, in4, in0, UP_S, 0, act, 2048, nullptr, CH, 1024, c * CH,
                dflag, xsel, nullptr, nullptr, nullptr, nullptr, 0, 0, 0);
            gemm_nt<0,0,0,0,0,1,0,1><<<dim3(1024 / 64, CH / 64), 256, 0, stream>>>(
                act, nullptr, 2048, w2s, nullptr, 0, 0,
                outS + (size_t)c * CH * 1024, 1024, nullptr, CH, 2048, 0,
                dflag, xsel, nullptr, nullptr, nullptr, nullptr, 0, 0, 0);
        }
    }
    (void)in_sizes; (void)n_in; (void)out_size;
}

// Round 6
// 385.004 us; speedup vs baseline: 1.5277x; 1.0702x over previous
//
#include <hip/hip_runtime.h>

// ---------------------------------------------------------------------------
// SharedFusedMoE on MI355X (gfx950). fp32 inputs, FP32 outputs.
// T=4096, D=1024, I=512 (routed), E=16, top-2, SI=2048 (shared).
// Round 12: launch-count collapse 14 -> 5. Round-5 accounting showed
// sum(dispatch dur) ~220us vs 412us total => ~190us of inter-dispatch
// overhead (~13us x 14 launches). setup_all merges probes+router+scan+pairs
// into one single-block kernel (LDS counts/cursors, no memset); conv_all
// merges the 5 bf16 conversions into one grid-stride kernel over the
// contiguous workspace region. GEMM kernels byte-identical to round 5
// (g2 split-K rebalance + T2 swizzle, bank conflicts measured 0).
// Output slot 0 = shared_out, slot 1 = fused_out (reference return order).
// ---------------------------------------------------------------------------

#define T_TOK 4096
#define NEXP  16

typedef __attribute__((ext_vector_type(8))) short   short8;   // 8 x bf16
typedef __attribute__((ext_vector_type(4))) float   floatx4;  // MFMA acc

typedef __attribute__((address_space(1))) void as1_void;
typedef __attribute__((address_space(3))) void as3_void;

__device__ __forceinline__ float bf2f(ushort u) {
    union { unsigned int i; float f; } v; v.i = ((unsigned int)u) << 16; return v.f;
}
__device__ __forceinline__ ushort f2bf(float f) {   // RNE, finite inputs
    unsigned int u = __builtin_bit_cast(unsigned int, f);
    unsigned int r = 0x7FFFu + ((u >> 16) & 1u);
    return (ushort)((u + r) >> 16);
}

__device__ __forceinline__ float load_elem(const void* p, long i, int bf) {
    return bf ? bf2f(((const ushort*)p)[i]) : ((const float*)p)[i];
}

// Router helper: softmax -> top-2 -> renormalize (denominators cancel).
// Tie-break = jax.lax.top_k (lowest index first).
__device__ __forceinline__ void top2(const void* logits, int t, int bf,
                                     int& b0, int& b1, float& w0, float& w1) {
    float l[16];
#pragma unroll
    for (int j = 0; j < 16; ++j) l[j] = load_elem(logits, t * 16 + j, bf);
    b0 = 0; float v0 = l[0];
#pragma unroll
    for (int j = 1; j < 16; ++j) { if (l[j] > v0) { v0 = l[j]; b0 = j; } }
    b1 = -1; float v1 = -3.4e38f;
#pragma unroll
    for (int j = 0; j < 16; ++j) {
        if (j == b0) continue;
        if (l[j] > v1) { v1 = l[j]; b1 = j; }
    }
    float d = __expf(v1 - v0);
    w0 = 1.0f / (1.0f + d);
    w1 = d / (1.0f + d);
}

// ---------------------------------------------------------------------------
// setup_all: ONE single-block kernel = dtype probe + xsel probe + router
// counts + scan + pair building. 1024 threads (16 waves), 4 tokens/thread.
// Replaces 6 launches (detect_dtype, detect_xsel, memset, router_counts,
// scan_kernel, router_pairs).
// ---------------------------------------------------------------------------
__global__ __launch_bounds__(1024)
void setup_all(const void* __restrict__ in0, const void* __restrict__ in4,
               const void* __restrict__ logits,
               int* __restrict__ dflag, int* __restrict__ xsel,
               int* __restrict__ counts, int* __restrict__ offsets,
               int* __restrict__ pairinfo, float* __restrict__ pairw)
{
    __shared__ int   s_cnt[16], s_off[16], s_cur[16];
    __shared__ int   s_dcnt, s_dflag, s_xsel;
    __shared__ float s0s, s4s;
    const int tid = threadIdx.x;

    if (tid < 16) { s_cnt[tid] = 0; s_cur[tid] = 0; }
    if (tid == 0) { s_dcnt = 0; s0s = 0.f; s4s = 0.f; }
    __syncthreads();

    // --- dtype probe: even ushort indices are bf16-looking if bf16 input ---
    if (tid < 256) {
        const ushort* xu = (const ushort*)in0;
        int ok = 0;
        for (int i = tid; i < 512; i += 256) {
            int e = (xu[2 * i] >> 7) & 0xFF;
            ok += (e >= 90 && e <= 140) ? 1 : 0;
        }
        atomicAdd(&s_dcnt, ok);
    }
    __syncthreads();
    if (tid == 0) { s_dflag = (s_dcnt >= 384) ? 1 : 0; *dflag = s_dflag; }
    __syncthreads();
    const int bf = s_dflag;

    // --- xsel probe: |hidden| ~ 1.0 vs |w13_shared| ~ 1/32 ---
    if (tid < 256) {
        float a0 = 0.f, a4 = 0.f;
        for (int i = tid; i < 4096; i += 256) {
            a0 += fabsf(load_elem(in0, (long)i * 997 + 13, bf));
            a4 += fabsf(load_elem(in4, (long)i * 997 + 13, bf));
        }
        atomicAdd(&s0s, a0);
        atomicAdd(&s4s, a4);
    }
    __syncthreads();
    if (tid == 0) { s_xsel = (s0s >= s4s) ? 0 : 1; *xsel = s_xsel; }

    // --- router pass 1: counts (top2 results kept in registers) ---
    int   b0[4], b1[4];
    float w0[4], w1[4];
#pragma unroll
    for (int it = 0; it < 4; ++it) {
        const int t = tid + it * 1024;
        top2(logits, t, bf, b0[it], b1[it], w0[it], w1[it]);
        atomicAdd(&s_cnt[b0[it]], 1);
        atomicAdd(&s_cnt[b1[it]], 1);
    }
    __syncthreads();

    // --- scan ---
    if (tid == 0) {
        int acc = 0;
        for (int e = 0; e < NEXP; ++e) {
            s_off[e] = acc; offsets[e] = acc; counts[e] = s_cnt[e];
            acc += s_cnt[e];
        }
    }
    __syncthreads();

    // --- router pass 2: pairs via LDS cursors ---
#pragma unroll
    for (int it = 0; it < 4; ++it) {
        const int t = tid + it * 1024;
        int p0 = s_off[b0[it]] + atomicAdd(&s_cur[b0[it]], 1);
        pairinfo[p0] = 2 * t;     pairw[p0] = w0[it];
        int p1 = s_off[b1[it]] + atomicAdd(&s_cur[b1[it]], 1);
        pairinfo[p1] = 2 * t + 1; pairw[p1] = w1[it];
    }
}

// ---------------------------------------------------------------------------
// conv_all: ONE grid-stride kernel converting all five operand tensors into
// the contiguous bf16 region (FULL2/3/FULL layout: hidb | w13sb | w13b | w2b
// | w2sb). Replaces 5 to_bf16 launches. Units below are 8-element groups.
// ---------------------------------------------------------------------------
__global__ __launch_bounds__(256)
void conv_all(const void* __restrict__ in0, const void* __restrict__ in4,
              const void* __restrict__ w13, const void* __restrict__ w2,
              const void* __restrict__ w2s, ushort* __restrict__ dst,
              const int* __restrict__ dflag, const int* __restrict__ xsel)
{
    const int bf = *dflag, xs = *xsel;
    const long E0 = 524288;    // hid   [4096x1024]
    const long E1 = 1048576;   // w13s  [4096x1024]
    const long E2 = 3145728;   // w13   [16x1024x1024]
    const long E3 = 4194304;   // w2    [16x1024x512]
    const long E4 = 4456448;   // w2s   [1024x2048]
    long i = (long)blockIdx.x * blockDim.x + threadIdx.x;
    const long stride = (long)gridDim.x * blockDim.x;
    for (; i < E4; i += stride) {
        const void* src; long j;
        if      (i < E0) { src = xs ? in4 : in0; j = i;      }
        else if (i < E1) { src = xs ? in0 : in4; j = i - E0; }
        else if (i < E2) { src = w13;            j = i - E1; }
        else if (i < E3) { src = w2;             j = i - E2; }
        else             { src = w2s;            j = i - E3; }
        uint4 v;
        if (bf) {
            v = ((const uint4*)src)[j];
        } else {
            float4 f0 = ((const float4*)src)[j * 2];
            float4 f1 = ((const float4*)src)[j * 2 + 1];
            v.x = (unsigned)f2bf(f0.x) | ((unsigned)f2bf(f0.y) << 16);
            v.y = (unsigned)f2bf(f0.z) | ((unsigned)f2bf(f0.w) << 16);
            v.z = (unsigned)f2bf(f1.x) | ((unsigned)f2bf(f1.y) << 16);
            v.w = (unsigned)f2bf(f1.z) | ((unsigned)f2bf(f1.w) << 16);
        }
        ((uint4*)dst)[i] = v;
    }
}

// to_bf16 retained for the MID tier only.
__global__ void to_bf16(const void* __restrict__ pA, const void* __restrict__ pB,
                        ushort* __restrict__ dst, long n8,
                        const int* __restrict__ dflag, const int* __restrict__ xsel)
{
    const void* src = (pB != nullptr && *xsel) ? pB : pA;
    const int bf = *dflag;
    long i = (long)blockIdx.x * blockDim.x + threadIdx.x;
    const long stride = (long)gridDim.x * blockDim.x;
    for (; i < n8; i += stride) {
        uint4 v;
        if (bf) {
            v = ((const uint4*)src)[i];
        } else {
            float4 f0 = ((const float4*)src)[i * 2];
            float4 f1 = ((const float4*)src)[i * 2 + 1];
            v.x = (unsigned)f2bf(f0.x) | ((unsigned)f2bf(f0.y) << 16);
            v.y = (unsigned)f2bf(f0.z) | ((unsigned)f2bf(f0.w) << 16);
            v.z = (unsigned)f2bf(f1.x) | ((unsigned)f2bf(f1.y) << 16);
            v.w = (unsigned)f2bf(f1.z) | ((unsigned)f2bf(f1.w) << 16);
        }
        ((uint4*)dst)[i] = v;
    }
}

// ---------------------------------------------------------------------------
// m97-class bf16 NT GEMM core (unchanged from round 5; conflicts measured 0).
// 128-row tile, BK=64, 4 waves. Plain: BN=128 (4x4 frags). SWIGLU: BN=64
// gate+up. NARROW: BN=64 single-matrix (shared-w2 split-K).
// T2 swizzle (rule #21): linear global_load_lds dest + XOR-permuted per-lane
// global source col-group ((lane&7)^(lane>>3)) + matching XOR on fragment
// reads ((kc*4+quad)^(r16&7)).
// ---------------------------------------------------------------------------
__device__ __forceinline__ void gload16(const ushort* g, ushort* l) {
    __builtin_amdgcn_global_load_lds((as1_void*)g, (as3_void*)l, 16, 0, 0);
}

template <int SWIGLU, int GATHER, int ROUTED, int SCATTER, int NARROW = 0>
__device__ __forceinline__ void gemm_core(
    ushort* __restrict__ smem,
    const ushort* __restrict__ A, int lda,
    const ushort* __restrict__ B0, long upoff, long bbase, int ldb,
    void* __restrict__ C, int ldc, float* __restrict__ C2,
    int m0, int n0, int Mloc, int K, int pair_base,
    const int* __restrict__ pairinfo, const float* __restrict__ pairw)
{
    constexpr int BNRW = (SWIGLU || NARROW);   // 64-wide B tile
    constexpr int NBI = BNRW ? 2 : 4;     // B-stage instrs per wave per K-step
    constexpr int NFN = BNRW ? 2 : 4;     // 16-col frags per wave

    ushort* As  = smem;                       // 128 x 64
    ushort* Bs0 = smem + 128 * 64;            // BN x 64
    ushort* Bs1 = SWIGLU ? (smem + 128 * 64 + 64 * 64) : nullptr;

    const int tid  = threadIdx.x;
    const int lane = tid & 63;
    const int wave = tid >> 6;
    const int srow = lane >> 3;                      // row within 8-row group
    const int scol = ((lane & 7) ^ srow) * 8;        // swizzled source col grp

    long aoff[4];
#pragma unroll
    for (int i = 0; i < 4; ++i) {
        int rl  = m0 + (wave * 4 + i) * 8 + srow;
        int rlc = rl < Mloc ? rl : Mloc - 1;
        long gr;
        if (GATHER)      gr = (long)(pairinfo[pair_base + rlc] >> 1);
        else if (ROUTED) gr = pair_base + rlc;
        else             gr = rlc;
        aoff[i] = gr * (long)lda + scol;
    }
    long boff[NBI];
#pragma unroll
    for (int i = 0; i < NBI; ++i) {
        int r = (wave * NBI + i) * 8 + srow;
        boff[i] = bbase + (long)(n0 + r) * ldb + scol;
    }

    const int wm   = (wave >> 1) * 64;
    const int wn   = (wave & 1) * (BNRW ? 32 : 64);
    const int r16  = lane & 15;
    const int quad = lane >> 4;
    const int rlow = r16 & 7;

    const floatx4 z4 = {0.f, 0.f, 0.f, 0.f};
    floatx4 accg[4][NFN], accu[4][NFN];
#pragma unroll
    for (int mi = 0; mi < 4; ++mi)
#pragma unroll
        for (int ni = 0; ni < NFN; ++ni) { accg[mi][ni] = z4; accu[mi][ni] = z4; }

    for (int k0 = 0; k0 < K; k0 += 64) {
#pragma unroll
        for (int i = 0; i < 4; ++i)
            gload16(A + aoff[i] + k0, &As[(wave * 4 + i) * 512]);
#pragma unroll
        for (int i = 0; i < NBI; ++i) {
            gload16(B0 + boff[i] + k0, &Bs0[(wave * NBI + i) * 512]);
            if constexpr (SWIGLU)
                gload16(B0 + boff[i] + upoff + k0, &Bs1[(wave * NBI + i) * 512]);
        }
        __syncthreads();   // compiler drains vmcnt before s_barrier
#pragma unroll
        for (int kc = 0; kc < 2; ++kc) {
            const int sw = ((kc * 4 + quad) ^ rlow) * 8;   // swizzled 16B slot
            short8 af[4];
#pragma unroll
            for (int mi = 0; mi < 4; ++mi)
                af[mi] = *(const short8*)&As[(wm + mi * 16 + r16) * 64 + sw];
            short8 bfr[NFN], ufr[NFN];
#pragma unroll
            for (int ni = 0; ni < NFN; ++ni) {
                bfr[ni] = *(const short8*)&Bs0[(wn + ni * 16 + r16) * 64 + sw];
                if constexpr (SWIGLU)
                    ufr[ni] = *(const short8*)&Bs1[(wn + ni * 16 + r16) * 64 + sw];
            }
#pragma unroll
            for (int mi = 0; mi < 4; ++mi)
#pragma unroll
                for (int ni = 0; ni < NFN; ++ni) {
                    accg[mi][ni] = __builtin_amdgcn_mfma_f32_16x16x32_bf16(
                        af[mi], bfr[ni], accg[mi][ni], 0, 0, 0);
                    if constexpr (SWIGLU)
                        accu[mi][ni] = __builtin_amdgcn_mfma_f32_16x16x32_bf16(
                            af[mi], ufr[ni], accu[mi][ni], 0, 0, 0);
                }
        }
        __syncthreads();
    }

#pragma unroll
    for (int mi = 0; mi < 4; ++mi) {
#pragma unroll
        for (int r = 0; r < 4; ++r) {
            const int grow = m0 + wm + mi * 16 + quad * 4 + r;
            if (grow >= Mloc) continue;
            int info = 0; float w = 0.f;
            if constexpr (SCATTER) {
                const int p = pair_base + grow;
                info = pairinfo[p]; w = pairw[p];
            }
#pragma unroll
            for (int ni = 0; ni < NFN; ++ni) {
                const int col = n0 + wn + ni * 16 + r16;
                float val;
                if constexpr (SWIGLU) {
                    float g = accg[mi][ni][r];
                    float u = accu[mi][ni][r];
                    val = (g / (1.0f + __expf(-g))) * u;   // silu(g)*u
                } else {
                    val = accg[mi][ni][r];
                }
                if constexpr (SCATTER) {
                    long idx = (long)(info >> 1) * 1024 + col;
                    float* dst = (info & 1) ? C2 : (float*)C;
                    dst[idx] = w * val;
                } else if constexpr (SWIGLU) {
                    long crow = ROUTED ? (long)(pair_base + grow) : (long)grow;
                    ((ushort*)C)[crow * ldc + col] = f2bf(val);   // bf16 act
                } else {
                    ((float*)C)[(long)grow * ldc + col] = val;    // fp32 out
                }
            }
        }
    }
}

// Thin wrapper (FULL / MID tiers).
template <int SWIGLU, int GATHER, int ROUTED, int SCATTER>
__global__ __launch_bounds__(256)
void gemm_fast(const ushort* __restrict__ A, int lda,
               const ushort* __restrict__ B0, long upoff, long strideB, int ldb,
               void* __restrict__ C, int ldc, float* __restrict__ C2,
               int M, int K,
               const int* __restrict__ counts, const int* __restrict__ offsets,
               const int* __restrict__ pairinfo, const float* __restrict__ pairw)
{
    __shared__ __align__(16) ushort smem[16384];
    const int e    = ROUTED ? (int)blockIdx.z : 0;
    const int Mloc = ROUTED ? counts[e] : M;
    const int m0   = blockIdx.y * 128;
    if (m0 >= Mloc) return;
    constexpr int BN = SWIGLU ? 64 : 128;
    const int n0  = blockIdx.x * BN;
    const int pb  = ROUTED ? offsets[e] : 0;
    const long bb = ROUTED ? (long)e * strideB : 0L;
    gemm_core<SWIGLU, GATHER, ROUTED, SCATTER>(
        smem, A, lda, B0, upoff, bb, ldb, C, ldc, C2,
        m0, n0, Mloc, K, pb, pairinfo, pairw);
}

// Fused L1: routed w13-SwiGLU (z<4, 4 experts per z-slice) + shared w13-SwiGLU
// (z==4). Grid (32, 32, 5).
__global__ __launch_bounds__(256)
void g1_fused(const ushort* __restrict__ hidb, const ushort* __restrict__ w13b,
              const ushort* __restrict__ w13sb,
              ushort* __restrict__ actR, ushort* __restrict__ actS,
              const int* __restrict__ counts, const int* __restrict__ offsets,
              const int* __restrict__ pairinfo)
{
    __shared__ __align__(16) ushort smem[16384];
    const int z  = blockIdx.z;
    const int m0 = blockIdx.y * 128;
    if (z < 4) {
        const int e    = z * 4 + ((int)blockIdx.x >> 3);
        const int Mloc = counts[e];
        if (m0 >= Mloc) return;
        const int n0 = ((int)blockIdx.x & 7) * 64;
        gemm_core<1, 1, 1, 0>(smem, hidb, 1024,
                              w13b, (long)512 * 1024, (long)e * 1024 * 1024, 1024,
                              actR, 512, nullptr,
                              m0, n0, Mloc, 1024, offsets[e], pairinfo, nullptr);
    } else {
        const int n0 = (int)blockIdx.x * 64;
        gemm_core<1, 0, 0, 0>(smem, hidb, 1024,
                              w13sb, (long)2048 * 1024, 0L, 1024,
                              actS, 2048, nullptr,
                              m0, n0, T_TOK, 1024, 0, nullptr, nullptr);
    }
}

// Fused L2: routed w2 + scatter (rank0->outF, rank1->outT) (z<4) + shared w2.
// SPLIT=1: shared part is BN=64, split-K=2 (z=4 -> outS half-K, z=5 -> outP
// half-K); grid (32, 32, 6). SPLIT=0: legacy full-K z==4; grid (32, 32, 5).
template <int SPLIT>
__global__ __launch_bounds__(256)
void g2_fused(const ushort* __restrict__ actR, const ushort* __restrict__ actS,
              const ushort* __restrict__ w2b, const ushort* __restrict__ w2sb,
              float* __restrict__ outF, float* __restrict__ outT,
              float* __restrict__ outS, float* __restrict__ outP,
              const int* __restrict__ counts, const int* __restrict__ offsets,
              const int* __restrict__ pairinfo, const float* __restrict__ pairw)
{
    __shared__ __align__(16) ushort smem[16384];
    const int z  = blockIdx.z;
    const int m0 = blockIdx.y * 128;
    if (z < 4) {
        const int e    = z * 4 + ((int)blockIdx.x >> 3);
        const int Mloc = counts[e];
        if (m0 >= Mloc) return;
        const int n0 = ((int)blockIdx.x & 7) * 128;
        gemm_core<0, 0, 1, 1>(smem, actR, 512,
                              w2b, 0L, (long)e * 1024 * 512, 512,
                              outF, 1024, outT,
                              m0, n0, Mloc, 512, offsets[e], pairinfo, pairw);
    } else if constexpr (SPLIT) {
        const int zz = z - 4;                 // K-half index
        if ((int)blockIdx.x >= 16) return;
        const int n0 = (int)blockIdx.x * 64;
        gemm_core<0, 0, 0, 0, 1>(smem, actS + zz * 1024, 2048,
                                 w2sb + zz * 1024, 0L, 0L, 2048,
                                 zz ? outP : outS, 1024, nullptr,
                                 m0, n0, T_TOK, 1024, 0, nullptr, nullptr);
    } else {
        if ((int)blockIdx.x >= 8) return;
        const int n0 = (int)blockIdx.x * 128;
        gemm_core<0, 0, 0, 0>(smem, actS, 2048,
                              w2sb, 0L, 0L, 2048,
                              outS, 1024, nullptr,
                              m0, n0, T_TOK, 2048, 0, nullptr, nullptr);
    }
}

// outF[i] += outT[i]   (fp32, 4 elems/thread)
__global__ void add_kernel(float* __restrict__ outF, const float* __restrict__ outT, int n4) {
    int i = blockIdx.x * blockDim.x + threadIdx.x;
    if (i >= n4) return;
    float4 a = *(const float4*)(outF + (long)i * 4);
    float4 b = *(const float4*)(outT + (long)i * 4);
    a.x += b.x; a.y += b.y; a.z += b.z; a.w += b.w;
    *(float4*)(outF + (long)i * 4) = a;
}

// Fused reductions: outF += outT (fused rank1) and outS += outP (shared K-half).
__global__ void add2_kernel(float* __restrict__ outF, const float* __restrict__ outT,
                            float* __restrict__ outS, const float* __restrict__ outP,
                            int n4) {
    int i = blockIdx.x * blockDim.x + threadIdx.x;
    if (i < n4) {
        float4 a = *(const float4*)(outF + (long)i * 4);
        float4 b = *(const float4*)(outT + (long)i * 4);
        a.x += b.x; a.y += b.y; a.z += b.z; a.w += b.w;
        *(float4*)(outF + (long)i * 4) = a;
    } else if (i < 2 * n4) {
        int j = i - n4;
        float4 a = *(const float4*)(outS + (long)j * 4);
        float4 b = *(const float4*)(outP + (long)j * 4);
        a.x += b.x; a.y += b.y; a.z += b.z; a.w += b.w;
        *(float4*)(outS + (long)j * 4) = a;
    }
}

// ---------------------------------------------------------------------------
// Fallback GEMM (original session kernel) — tiny-ws insurance only.
// ---------------------------------------------------------------------------
__device__ __forceinline__ void stage8(const void* __restrict__ src, long eoff, int bf,
                                       ushort* __restrict__ dst) {
    if (bf) {
        *(uint4*)dst = *(const uint4*)((const ushort*)src + eoff);
    } else {
        const float* s = (const float*)src + eoff;
        float4 f0 = *(const float4*)s;
        float4 f1 = *(const float4*)(s + 4);
        uint4 v;
        v.x = (unsigned)f2bf(f0.x) | ((unsigned)f2bf(f0.y) << 16);
        v.y = (unsigned)f2bf(f0.z) | ((unsigned)f2bf(f0.w) << 16);
        v.z = (unsigned)f2bf(f1.x) | ((unsigned)f2bf(f1.y) << 16);
        v.w = (unsigned)f2bf(f1.z) | ((unsigned)f2bf(f1.w) << 16);
        *(uint4*)dst = v;
    }
}

template <int SWIGLU, int GATHER, int ROUTED, int SCATTER, int LOCAL,
          int A_DT, int B_DT, int C_F32>
__global__ __launch_bounds__(256)
void gemm_nt(const void* __restrict__ A, const void* __restrict__ Aalt, int lda,
             const void* __restrict__ B0, const void* __restrict__ B0alt,
             long upoff, long strideB,
             void* __restrict__ C, int ldc, void* __restrict__ C2,
             int M, int K, int row0,
             const int* __restrict__ dflag, const int* __restrict__ xsel,
             const int* __restrict__ counts, const int* __restrict__ offsets,
             const int* __restrict__ pairinfo, const float* __restrict__ pairw,
             int e_base, int m_base, int Mcap)
{
    const int dfl = (A_DT && B_DT) ? 1 : *dflag;
    const int abf = A_DT ? 1 : dfl;
    const int bbf = B_DT ? 1 : dfl;
    if (Aalt  && *xsel) A  = Aalt;
    if (B0alt && *xsel) B0 = B0alt;

    const int e = ROUTED ? (e_base + (int)blockIdx.z) : 0;
    int Mloc;
    if (ROUTED) {
        int avail = counts[e] - m_base;
        Mloc = avail < Mcap ? avail : Mcap;
    } else {
        Mloc = M;
    }
    const int m0 = blockIdx.y * 64;
    if (m0 >= Mloc) return;
    const int n0 = blockIdx.x * 64;
    const int pair_base = ROUTED ? (offsets[e] + m_base) : 0;
    const int abase     = ROUTED ? (LOCAL ? 0 : offsets[e]) : 0;
    const long bbase    = ROUTED ? (long)e * strideB : 0L;

    constexpr int LS = 72;
    __shared__ __align__(16) ushort As[64 * LS];
    __shared__ __align__(16) ushort Bs0[64 * LS];
    __shared__ __align__(16) ushort Bs1[SWIGLU ? 64 * LS : 8];

    const int tid = threadIdx.x;

    int  lofs[2];
    long aoff[2], boff[2];
#pragma unroll
    for (int i = 0; i < 2; ++i) {
        int idx = tid + i * 256;
        int row = idx >> 3;
        int col = (idx & 7) * 8;
        lofs[i] = row * LS + col;
        int rl  = m0 + row;
        int rlc = rl < Mloc ? rl : (Mloc - 1);
        long rA;
        if (GATHER)      rA = (long)(pairinfo[pair_base + rlc] >> 1);
        else if (ROUTED) rA = abase + rlc;
        else             rA = row0 + rl;
        aoff[i] = rA * (long)lda + col;
        boff[i] = bbase + (long)(n0 + row) * K + col;
    }

    const int lane = tid & 63;
    const int wave = tid >> 6;
    const int wm   = (wave >> 1) * 32;
    const int wn   = (wave & 1) * 32;
    const int r16  = lane & 15;
    const int quad = lane >> 4;

    floatx4 accg[2][2] = {{{0.f,0.f,0.f,0.f},{0.f,0.f,0.f,0.f}},{{0.f,0.f,0.f,0.f},{0.f,0.f,0.f,0.f}}};
    floatx4 accu[2][2] = {{{0.f,0.f,0.f,0.f},{0.f,0.f,0.f,0.f}},{{0.f,0.f,0.f,0.f},{0.f,0.f,0.f,0.f}}};

    for (int k0 = 0; k0 < K; k0 += 64) {
#pragma unroll
        for (int i = 0; i < 2; ++i) {
            stage8(A,  aoff[i] + k0, abf, &As[lofs[i]]);
            stage8(B0, boff[i] + k0, bbf, &Bs0[lofs[i]]);
            if (SWIGLU) stage8(B0, boff[i] + k0 + upoff, bbf, &Bs1[lofs[i]]);
        }
        __syncthreads();
#pragma unroll
        for (int kc = 0; kc < 2; ++kc) {
            const int kof = kc * 32 + quad * 8;
            short8 a0 = *(const short8*)&As[(wm + r16)      * LS + kof];
            short8 a1 = *(const short8*)&As[(wm + 16 + r16) * LS + kof];
            short8 b0 = *(const short8*)&Bs0[(wn + r16)      * LS + kof];
            short8 b1 = *(const short8*)&Bs0[(wn + 16 + r16) * LS + kof];
            accg[0][0] = __builtin_amdgcn_mfma_f32_16x16x32_bf16(a0, b0, accg[0][0], 0, 0, 0);
            accg[0][1] = __builtin_amdgcn_mfma_f32_16x16x32_bf16(a0, b1, accg[0][1], 0, 0, 0);
            accg[1][0] = __builtin_amdgcn_mfma_f32_16x16x32_bf16(a1, b0, accg[1][0], 0, 0, 0);
            accg[1][1] = __builtin_amdgcn_mfma_f32_16x16x32_bf16(a1, b1, accg[1][1], 0, 0, 0);
            if (SWIGLU) {
                short8 u0 = *(const short8*)&Bs1[(wn + r16)      * LS + kof];
                short8 u1 = *(const short8*)&Bs1[(wn + 16 + r16) * LS + kof];
                accu[0][0] = __builtin_amdgcn_mfma_f32_16x16x32_bf16(a0, u0, accu[0][0], 0, 0, 0);
                accu[0][1] = __builtin_amdgcn_mfma_f32_16x16x32_bf16(a0, u1, accu[0][1], 0, 0, 0);
                accu[1][0] = __builtin_amdgcn_mfma_f32_16x16x32_bf16(a1, u0, accu[1][0], 0, 0, 0);
                accu[1][1] = __builtin_amdgcn_mfma_f32_16x16x32_bf16(a1, u1, accu[1][1], 0, 0, 0);
            }
        }
        __syncthreads();
    }

#pragma unroll
    for (int mi = 0; mi < 2; ++mi) {
#pragma unroll
        for (int ni = 0; ni < 2; ++ni) {
#pragma unroll
            for (int r = 0; r < 4; ++r) {
                int rowl = wm + mi * 16 + quad * 4 + r;
                int grow = m0 + rowl;
                if (grow < Mloc) {
                    int col = n0 + wn + ni * 16 + r16;
                    float g = accg[mi][ni][r];
                    float val;
                    if (SWIGLU) {
                        float u = accu[mi][ni][r];
                        val = (g / (1.0f + __expf(-g))) * u;
                    } else {
                        val = g;
                    }
                    if (SCATTER) {
                        int p    = pair_base + grow;
                        int info = pairinfo[p];
                        float w  = pairw[p];
                        long idx = (long)(info >> 1) * 1024 + col;
                        void* dst = (info & 1) ? C2 : C;
                        if (C_F32) ((float*)dst)[idx]  = w * val;
                        else       ((ushort*)dst)[idx] = f2bf(w * val);
                    } else {
                        int crow = ROUTED ? (abase + grow) : grow;
                        long idx = (long)crow * ldc + col;
                        if (C_F32) ((float*)C)[idx]  = val;
                        else       ((ushort*)C)[idx] = f2bf(val);
                    }
                }
            }
        }
    }
}

// ---------------------------------------------------------------------------
extern "C" void kernel_launch(void* const* d_in, const int* in_sizes, int n_in,
                              void* d_out, int out_size, void* d_ws, size_t ws_size,
                              hipStream_t stream)
{
    const void* in0  = d_in[0];  // hidden_states [4096,1024] fp32
    const void* rl   = d_in[1];  // router_logits [4096,16]
    const void* w13  = d_in[2];  // [16,1024,1024]
    const void* w2   = d_in[3];  // [16,1024,512]
    const void* in4  = d_in[4];  // w13_shared [4096,1024]
    const void* w2s  = d_in[5];  // w2_shared [1024,2048]
    float* outS = (float*)d_out;                          // shared (final)
    float* outF = (float*)d_out + (size_t)T_TOK * 1024;   // fused (final)

    // ---- metadata layout (66 KB) ----
    char*  base     = (char*)d_ws;
    int*   counts   = (int*)(base);
    int*   dflag    = (int*)(base + 128);
    int*   xsel     = (int*)(base + 132);
    int*   offsets  = (int*)(base + 192);
    int*   pairinfo = (int*)(base + 256);
    float* pairw    = (float*)(base + 256 + 32768);
    const size_t META = 256 + 65536;

    size_t avail = ws_size > META ? ws_size - META : 0;

    // ---- ONE setup launch: probes + router counts/scan/pairs ----
    setup_all<<<1, 1024, 0, stream>>>(in0, in4, rl, dflag, xsel,
                                      counts, offsets, pairinfo, pairw);

    const long sB1  = (long)1024 * 1024;   // w13 per-expert elements
    const long sB2  = (long)1024 * 512;    // w2 per-expert elements
    const long UP_R = (long)512 * 1024;    // routed up-offset within expert block
    const long UP_S = (long)2048 * 1024;   // shared up-offset in w13s

    const size_t FULL3_NEED = 113246208ULL; // FULL2 + 16MB outP (split-K partial)
    const size_t FULL2_NEED = 96468992ULL;  // all-bf16 + actR + actS (outT aliases hidb+w13sb)
    const size_t FULL_NEED  = 88080384ULL;  // all-bf16 + single shared act
    const size_t MID_NEED   = 29360128ULL;  // act + hid + w13s + w2s bf16

    if (avail >= FULL2_NEED) {
        // ============ FULL2/3: bf16 everywhere + fused launches ===========
        ushort* hidb  = (ushort*)(base + META);
        ushort* w13sb = hidb  + (size_t)4096 * 1024;
        ushort* w13b  = w13sb + (size_t)4096 * 1024;
        ushort* w2b   = w13b  + (size_t)16 * 1024 * 1024;
        ushort* w2sb  = w2b   + (size_t)16 * 1024 * 512;
        ushort* actR  = w2sb  + (size_t)1024 * 2048;     // [8192, 512] bf16
        ushort* actS  = actR  + (size_t)8192 * 512;      // [4096, 2048] bf16
        float*  outP  = (float*)(actS + (size_t)4096 * 2048);  // FULL3 only
        float*  outT  = (float*)hidb;   // rank1 temp; aliases hidb+w13sb (dead after g1)

        // ONE conversion launch for all five tensors (contiguous dst region).
        conv_all<<<2048, 256, 0, stream>>>(in0, in4, w13, w2, w2s,
                                           hidb, dflag, xsel);

        g1_fused<<<dim3(32, 32, 5), 256, 0, stream>>>(
            hidb, w13b, w13sb, actR, actS, counts, offsets, pairinfo);

        if (avail >= FULL3_NEED) {
            g2_fused<1><<<dim3(32, 32, 6), 256, 0, stream>>>(
                actR, actS, w2b, w2sb, outF, outT, outS, outP,
                counts, offsets, pairinfo, pairw);
            add2_kernel<<<(2 * (T_TOK * 1024 / 4) + 255) / 256, 256, 0, stream>>>(
                outF, outT, outS, outP, T_TOK * 1024 / 4);
        } else {
            g2_fused<0><<<dim3(32, 32, 5), 256, 0, stream>>>(
                actR, actS, w2b, w2sb, outF, outT, outS, nullptr,
                counts, offsets, pairinfo, pairw);
            add_kernel<<<(T_TOK * 1024 / 4 + 255) / 256, 256, 0, stream>>>(
                outF, outT, T_TOK * 1024 / 4);
        }
    } else if (avail >= FULL_NEED) {
        // ====== FULL: bf16 everywhere, sequential launches (FULL2 buffer
        // order so conv_all applies; single act buffer) ======
        ushort* hidb  = (ushort*)(base + META);
        ushort* w13sb = hidb  + (size_t)4096 * 1024;
        ushort* w13b  = w13sb + (size_t)4096 * 1024;
        ushort* w2b   = w13b  + (size_t)16 * 1024 * 1024;
        ushort* w2sb  = w2b   + (size_t)16 * 1024 * 512;
        ushort* actb  = w2sb  + (size_t)1024 * 2048;

        conv_all<<<2048, 256, 0, stream>>>(in0, in4, w13, w2, w2s,
                                           hidb, dflag, xsel);

        gemm_fast<1,1,1,0><<<dim3(8, 32, NEXP), 256, 0, stream>>>(
            hidb, 1024, w13b, UP_R, sB1, 1024, actb, 512, nullptr, 0, 1024,
            counts, offsets, pairinfo, pairw);
        gemm_fast<0,0,1,1><<<dim3(8, 32, NEXP), 256, 0, stream>>>(
            actb, 512, w2b, 0, sB2, 512, outF, 1024, outS, 0, 512,
            counts, offsets, pairinfo, pairw);
        add_kernel<<<(T_TOK * 1024 / 4 + 255) / 256, 256, 0, stream>>>(outF, outS, T_TOK * 1024 / 4);
        gemm_fast<1,0,0,0><<<dim3(32, 32), 256, 0, stream>>>(
            hidb, 1024, w13sb, UP_S, 0, 1024, actb, 2048, nullptr, 4096, 1024,
            nullptr, nullptr, nullptr, nullptr);
        gemm_fast<0,0,0,0><<<dim3(8, 32), 256, 0, stream>>>(
            actb, 2048, w2sb, 0, 0, 2048, outS, 1024, nullptr, 4096, 2048,
            nullptr, nullptr, nullptr, nullptr);
    } else if (avail >= MID_NEED) {
        // ========== MID: fast shared path + improved old routed path =======
        ushort* act   = (ushort*)(base + META);
        ushort* hidb  = act   + (size_t)8192 * 512;
        ushort* w13sb = hidb  + (size_t)4096 * 1024;
        ushort* w2sb  = w13sb + (size_t)4096 * 1024;

        to_bf16<<<1024, 256, 0, stream>>>(in0, in4, hidb,  (long)4096 * 1024 / 8, dflag, xsel);
        to_bf16<<<1024, 256, 0, stream>>>(in4, in0, w13sb, (long)4096 * 1024 / 8, dflag, xsel);
        to_bf16<<<1024, 256, 0, stream>>>(w2s, nullptr, w2sb, (long)1024 * 2048 / 8, dflag, xsel);

        gemm_nt<1,1,1,0,0,1,0,0><<<dim3(8, 64, NEXP), 256, 0, stream>>>(
            hidb, nullptr, 1024, w13, nullptr, UP_R, sB1, act, 512, nullptr, 0, 1024, 0,
            dflag, xsel, counts, offsets, pairinfo, pairw, 0, 0, T_TOK);
        gemm_nt<0,0,1,1,0,1,0,1><<<dim3(16, 64, NEXP), 256, 0, stream>>>(
            act, nullptr, 512, w2, nullptr, 0, sB2, outF, 1024, outS, 0, 512, 0,
            dflag, xsel, counts, offsets, pairinfo, pairw, 0, 0, T_TOK);
        add_kernel<<<(T_TOK * 1024 / 4 + 255) / 256, 256, 0, stream>>>(outF, outS, T_TOK * 1024 / 4);
        for (int c = 0; c < 2; ++c) {
            gemm_fast<1,0,0,0><<<dim3(32, 16), 256, 0, stream>>>(
                hidb + (size_t)c * 2048 * 1024, 1024, w13sb, UP_S, 0, 1024,
                act, 2048, nullptr, 2048, 1024, nullptr, nullptr, nullptr, nullptr);
            gemm_fast<0,0,0,0><<<dim3(8, 16), 256, 0, stream>>>(
                act, 2048, w2sb, 0, 0, 2048, outS + (size_t)c * 2048 * 1024, 1024, nullptr,
                2048, 2048, nullptr, nullptr, nullptr, nullptr);
        }
    } else {
        // ===================== fallback: original kernel ===================
        const size_t MB = 1024 * 1024;
        int grouped, Mcap, CH;
        if      (avail >= 8 * MB) { grouped = 1; Mcap = T_TOK; CH = 2048; }
        else if (avail >= 1 * MB) { grouped = 0; Mcap = 1024;  CH = 256;  }
        else                      { grouped = 0; Mcap = 256;   CH = 64;   }
        ushort* act = (ushort*)(base + META);

        if (grouped) {
            gemm_nt<1,1,1,0,0,0,0,0><<<dim3(8, 64, NEXP), 256, 0, stream>>>(
                in0, in4, 1024, w13, nullptr, UP_R, sB1, act, 512, nullptr, 0, 1024, 0,
                dflag, xsel, counts, offsets, pairinfo, pairw, 0, 0, T_TOK);
            gemm_nt<0,0,1,1,0,1,0,1><<<dim3(16, 64, NEXP), 256, 0, stream>>>(
                act, nullptr, 512, w2, nullptr, 0, sB2, outF, 1024, outS, 0, 512, 0,
                dflag, xsel, counts, offsets, pairinfo, pairw, 0, 0, T_TOK);
        } else {
            for (int e = 0; e < NEXP; ++e) {
                for (int mb = 0; mb < T_TOK; mb += Mcap) {
                    gemm_nt<1,1,1,0,1,0,0,0><<<dim3(8, Mcap / 64, 1), 256, 0, stream>>>(
                        in0, in4, 1024, w13, nullptr, UP_R, sB1, act, 512, nullptr, 0, 1024, 0,
                        dflag, xsel, counts, offsets, pairinfo, pairw, e, mb, Mcap);
                    gemm_nt<0,0,1,1,1,1,0,1><<<dim3(16, Mcap / 64, 1), 256, 0, stream>>>(
                        act, nullptr, 512, w2, nullptr, 0, sB2, outF, 1024, outS, 0, 512, 0,
                        dflag, xsel, counts, offsets, pairinfo, pairw, e, mb, Mcap);
                }
            }
        }
        add_kernel<<<(T_TOK * 1024 / 4 + 255) / 256, 256, 0, stream>>>(outF, outS, T_TOK * 1024 / 4);
        for (int c = 0; c < T_TOK / CH; ++c) {
            gemm_nt<1,0,0,0,0,0,0,0><<<dim3(2048 / 64, CH / 64), 256, 0, stream>>>(
                in0, in4, 1024, in4, in0, UP_S, 0, act, 2048, nullptr, CH, 1024, c * CH,
                dflag, xsel, nullptr, nullptr, nullptr, nullptr, 0, 0, 0);
            gemm_nt<0,0,0,0,0,1,0,1><<<dim3(1024 / 64, CH / 64), 256, 0, stream>>>(
                act, nullptr, 2048, w2s, nullptr, 0, 0,
                outS + (size_t)c * CH * 1024, 1024, nullptr, CH, 2048, 0,
                dflag, xsel, nullptr, nullptr, nullptr, nullptr, 0, 0, 0);
        }
    }
    (void)in_sizes; (void)n_in; (void)out_size;
}